// Round 1
// baseline (488.457 us; speedup 1.0000x reference)
//
#include <hip/hip_runtime.h>

typedef _Float16 f16;
typedef _Float16 f16x8 __attribute__((ext_vector_type(8)));
typedef float f32x4 __attribute__((ext_vector_type(4)));

#define MFMA16(a, b, c) __builtin_amdgcn_mfma_f32_16x16x32_f16((a), (b), (c), 0, 0, 0)

#define BATCH 32768

// workspace layout (bytes)
#define OFF_XP      ((size_t)0)                    // xp: B*704 f16 = 46,137,344  (reused as e1P: B*640 f16)
#define OFF_MAGP    ((size_t)46137344)             // magP: B*832 f16 = 54,525,952
#define OFF_GATESA  ((size_t)(46137344 + 54525952))        // gatesA: B*256 f16 = 16,777,216
#define OFF_BF      (OFF_GATESA + 16777216)        // basis f16 [288][256]
#define OFF_W1      (OFF_BF + 147456)              // [128][416]
#define OFF_W2      (OFF_W1 + 106496)              // [64][384]
#define OFF_W3      (OFF_W2 + 49152)               // [64][192]
#define OFF_W4      (OFF_W3 + 24576)               // [128][64]
#define OFF_WG      (OFF_W4 + 16384)               // [512][256]

__device__ __forceinline__ float sigmoid_(float x) { return 1.f / (1.f + __expf(-x)); }

// ---------------------------------------------------------------------------
// prep: build xp (reflect-padded signal), zero magP pad positions, write h0
// into gatesA[:,128:256], and cast/transpose all weights into GEMM layouts.
// ---------------------------------------------------------------------------
__global__ __launch_bounds__(256) void prep_kernel(
    const float* __restrict__ x, const float* __restrict__ h0,
    const float* __restrict__ basis, const float* __restrict__ w1,
    const float* __restrict__ w2, const float* __restrict__ w3,
    const float* __restrict__ w4, const float* __restrict__ w_ih,
    const float* __restrict__ w_hh,
    f16* __restrict__ xp, f16* __restrict__ magP, f16* __restrict__ gatesA,
    f16* __restrict__ Bf, f16* __restrict__ W1, f16* __restrict__ W2,
    f16* __restrict__ W3, f16* __restrict__ W4, f16* __restrict__ Wg) {
  int blk = blockIdx.x;
  int tid = threadIdx.x;
  if (blk < 1024) {
    int b0 = blk * 32;
    // xp[b][j], j in [0,704): reflect pad of [zeros(64), x] by 64 each side
    for (int idx = tid; idx < 32 * 704; idx += 256) {
      int bl = idx / 704, j = idx - bl * 704;
      int b = b0 + bl;
      float v;
      if (j == 0) v = x[b * 512];           // left reflect hits x[0]
      else if (j < 128) v = 0.f;            // rest of left reflect + ctx zeros
      else if (j < 640) v = x[b * 512 + (j - 128)];
      else v = x[b * 512 + (510 - (j - 640))];  // right reflect
      xp[b * 704 + j] = (f16)v;
    }
    // magP zero pads: storage positions -1 (off [0,136)) and 4.. ([680,832))
    for (int idx = tid; idx < 32 * 288; idx += 256) {
      int bl = idx / 288, j = idx - bl * 288;
      int jj = (j < 136) ? j : (680 + (j - 136));
      magP[(b0 + bl) * 832 + jj] = (f16)0.f;
    }
    // gatesA[:,128:256) = f16(h0)
    for (int idx = tid; idx < 32 * 128; idx += 256) {
      int bl = idx >> 7, j = idx & 127;
      gatesA[(b0 + bl) * 256 + 128 + j] = (f16)h0[(b0 + bl) * 128 + j];
    }
  } else {
    int t = (blk - 1024) * 256 + tid;  // 0..16383
    // basis -> Bf[288][256] (rows >=258 zero)
    for (int idx = t; idx < 288 * 256; idx += 16384) {
      int n = idx >> 8, k = idx & 255;
      Bf[idx] = (f16)((n < 258) ? basis[n * 256 + k] : 0.f);
    }
    // w1 (128,129,3) -> W1[n][k], k = tap*136 + i (gaps/overrun zero), K=416
    for (int idx = t; idx < 128 * 416; idx += 16384) {
      int n = idx / 416, k = idx - n * 416;
      int tap = k / 136, i = k - tap * 136;
      float v = (tap < 3 && i < 129) ? w1[(n * 129 + i) * 3 + tap] : 0.f;
      W1[idx] = (f16)v;
    }
    // w2 (64,128,3) -> W2[n][k], k = tap*128 + i, K=384
    for (int idx = t; idx < 64 * 384; idx += 16384) {
      int n = idx / 384, k = idx - n * 384;
      int tap = k >> 7, i = k & 127;
      W2[idx] = (f16)w2[(n * 128 + i) * 3 + tap];
    }
    // w3 (64,64,3) -> W3[n][k], k = tap*64 + i, K=192
    for (int idx = t; idx < 64 * 192; idx += 16384) {
      int n = idx / 192, k = idx - n * 192;
      int tap = k >> 6, i = k & 63;
      W3[idx] = (f16)w3[(n * 64 + i) * 3 + tap];
    }
    // w4 (128,64,3), only tap=1 contributes -> W4[n][i], K=64
    for (int idx = t; idx < 128 * 64; idx += 16384) {
      int n = idx >> 6, i = idx & 63;
      W4[idx] = (f16)w4[(n * 64 + i) * 3 + 1];
    }
    // Wg[512][256] = [w_ih | w_hh]
    for (int idx = t; idx < 512 * 256; idx += 16384) {
      int n = idx >> 8, k = idx & 255;
      Wg[idx] = (f16)((k < 128) ? w_ih[n * 128 + k] : w_hh[n * 128 + (k - 128)]);
    }
  }
}

// ---------------------------------------------------------------------------
// STFT GEMM + magnitude epilogue.
// M' = 4*B rows (m = b*4 + t), A row = xp[b][128*t .. +256), K=256.
// B = Bf[288][256]. One wave per block, wave tile M=32 x N=288 (18 n-tiles).
// Epilogue: ft -> LDS, mag = sqrt(re^2+im^2) (c, c+129) -> magP position t.
// ---------------------------------------------------------------------------
__global__ __launch_bounds__(64) void stft_kernel(
    const f16* __restrict__ xp, const f16* __restrict__ Bf,
    f16* __restrict__ magP) {
  __shared__ __align__(16) f16 lds[32 * 296];
  int lane = threadIdx.x;
  int l15 = lane & 15, quad = lane >> 4;
  int m0 = blockIdx.x * 32;

  f32x4 zero4 = {0.f, 0.f, 0.f, 0.f};
  f32x4 acc[2][18];
#pragma unroll
  for (int mt = 0; mt < 2; mt++)
#pragma unroll
    for (int nt = 0; nt < 18; nt++) acc[mt][nt] = zero4;

  const f16* aptr[2];
#pragma unroll
  for (int mt = 0; mt < 2; mt++) {
    int m = m0 + mt * 16 + l15;
    int b = m >> 2, t = m & 3;
    aptr[mt] = xp + (size_t)b * 704 + t * 128 + quad * 8;
  }
  const f16* bptr = Bf + (size_t)l15 * 256 + quad * 8;

  for (int k0 = 0; k0 < 256; k0 += 32) {
    f16x8 a0 = *(const f16x8*)(aptr[0] + k0);
    f16x8 a1 = *(const f16x8*)(aptr[1] + k0);
#pragma unroll
    for (int nt = 0; nt < 18; nt++) {
      f16x8 bf = *(const f16x8*)(bptr + (size_t)nt * 16 * 256 + k0);
      acc[0][nt] = MFMA16(a0, bf, acc[0][nt]);
      acc[1][nt] = MFMA16(a1, bf, acc[1][nt]);
    }
  }

  // spill ft tile to LDS (f16)
#pragma unroll
  for (int mt = 0; mt < 2; mt++)
#pragma unroll
    for (int nt = 0; nt < 18; nt++)
#pragma unroll
      for (int r = 0; r < 4; r++) {
        int row = mt * 16 + quad * 4 + r;
        int col = nt * 16 + l15;
        lds[row * 296 + col] = (f16)acc[mt][nt][r];
      }
  __syncthreads();

  // magnitude: c in [0,129), pairs (c, c+129)
  for (int r = 0; r < 32; r++) {
    int m = m0 + r;
    int b = m >> 2, t = m & 3;
    f16* out = magP + (size_t)b * 832 + (t + 1) * 136;
#pragma unroll
    for (int ci = 0; ci < 3; ci++) {
      int c = ci * 64 + lane;
      if (c <= 128) {
        float re = (float)lds[r * 296 + c];
        float im = (float)lds[r * 296 + c + 129];
        out[c] = (f16)sqrtf(re * re + im * im);
      }
    }
  }
}

// ---------------------------------------------------------------------------
// conv1 GEMM: M' = 4*B rows (m = b*4 + p), A row = magP[b] + p*136, K=416,
// N=128. Wave tile M=64 x N=128. Epilogue: +bias, relu -> e1P position p+1;
// also zeroes e1P position 0 (p == 0 rows).
// ---------------------------------------------------------------------------
__global__ __launch_bounds__(256) void conv1_kernel(
    const f16* __restrict__ magP, const f16* __restrict__ W1,
    const float* __restrict__ b1, f16* __restrict__ e1P) {
  int lane = threadIdx.x & 63, wv = threadIdx.x >> 6;
  int l15 = lane & 15, quad = lane >> 4;
  int m0 = (blockIdx.x * 4 + wv) * 64;

  f32x4 zero4 = {0.f, 0.f, 0.f, 0.f};
  f32x4 acc[4][8];
#pragma unroll
  for (int mt = 0; mt < 4; mt++)
#pragma unroll
    for (int nt = 0; nt < 8; nt++) acc[mt][nt] = zero4;

  const f16* aptr[4];
#pragma unroll
  for (int mt = 0; mt < 4; mt++) {
    int m = m0 + mt * 16 + l15;
    int b = m >> 2, p = m & 3;
    aptr[mt] = magP + (size_t)b * 832 + p * 136 + quad * 8;
  }
  const f16* bptr = W1 + (size_t)l15 * 416 + quad * 8;

  for (int k0 = 0; k0 < 416; k0 += 32) {
    f16x8 a[4];
#pragma unroll
    for (int mt = 0; mt < 4; mt++) a[mt] = *(const f16x8*)(aptr[mt] + k0);
#pragma unroll
    for (int nt = 0; nt < 8; nt++) {
      f16x8 bf = *(const f16x8*)(bptr + (size_t)nt * 16 * 416 + k0);
#pragma unroll
      for (int mt = 0; mt < 4; mt++) acc[mt][nt] = MFMA16(a[mt], bf, acc[mt][nt]);
    }
  }

  float bias[8];
#pragma unroll
  for (int nt = 0; nt < 8; nt++) bias[nt] = b1[nt * 16 + l15];

#pragma unroll
  for (int mt = 0; mt < 4; mt++)
#pragma unroll
    for (int r = 0; r < 4; r++) {
      int m = m0 + mt * 16 + quad * 4 + r;
      int b = m >> 2, p = m & 3;
#pragma unroll
      for (int nt = 0; nt < 8; nt++) {
        int c = nt * 16 + l15;
        float v = fmaxf(acc[mt][nt][r] + bias[nt], 0.f);
        e1P[(size_t)b * 640 + (p + 1) * 128 + c] = (f16)v;
        if (p == 0) e1P[(size_t)b * 640 + c] = (f16)0.f;  // zero pad position
      }
    }
}

// ---------------------------------------------------------------------------
// c234: conv2 -> conv3 -> conv4 fused; 64 batch rows per block (4 waves).
// conv2: M=128 (b,p2), K=384, N=64 -> e2P LDS [64][208] (pos -1..1)
// conv3: M=64, K=192 (LDS), N=64 -> e3 LDS [64][64]
// conv4: M=64, K=64 (LDS), N=128 -> gatesA[:,0:128)
// ---------------------------------------------------------------------------
__global__ __launch_bounds__(256) void c234_kernel(
    const f16* __restrict__ e1P, const f16* __restrict__ W2,
    const float* __restrict__ b2, const f16* __restrict__ W3,
    const float* __restrict__ b3, const f16* __restrict__ W4,
    const float* __restrict__ b4, f16* __restrict__ gatesA) {
  __shared__ __align__(16) f16 e2P[64 * 208];
  __shared__ __align__(16) f16 e3s[64 * 64];
  int tid = threadIdx.x;
  int lane = tid & 63, wv = tid >> 6;
  int l15 = lane & 15, quad = lane >> 4;
  int b0 = blockIdx.x * 64;
  f32x4 zero4 = {0.f, 0.f, 0.f, 0.f};

  // zero e2P storage position 0 (conv3's position -1)
  for (int i = tid; i < 64 * 64; i += 256) {
    int bl = i >> 6, c = i & 63;
    e2P[bl * 208 + c] = (f16)0.f;
  }
  __syncthreads();

  {  // conv2
    f32x4 acc[2][4];
#pragma unroll
    for (int mt = 0; mt < 2; mt++)
#pragma unroll
      for (int nt = 0; nt < 4; nt++) acc[mt][nt] = zero4;
    const f16* aptr[2];
#pragma unroll
    for (int mt = 0; mt < 2; mt++) {
      int m = wv * 32 + mt * 16 + l15;
      int bl = m >> 1, p2 = m & 1;
      aptr[mt] = e1P + (size_t)(b0 + bl) * 640 + p2 * 256 + quad * 8;
    }
    const f16* bptr = W2 + (size_t)l15 * 384 + quad * 8;
    for (int k0 = 0; k0 < 384; k0 += 32) {
      f16x8 a0 = *(const f16x8*)(aptr[0] + k0);
      f16x8 a1 = *(const f16x8*)(aptr[1] + k0);
#pragma unroll
      for (int nt = 0; nt < 4; nt++) {
        f16x8 bf = *(const f16x8*)(bptr + (size_t)nt * 16 * 384 + k0);
        acc[0][nt] = MFMA16(a0, bf, acc[0][nt]);
        acc[1][nt] = MFMA16(a1, bf, acc[1][nt]);
      }
    }
    float bias[4];
#pragma unroll
    for (int nt = 0; nt < 4; nt++) bias[nt] = b2[nt * 16 + l15];
#pragma unroll
    for (int mt = 0; mt < 2; mt++)
#pragma unroll
      for (int r = 0; r < 4; r++) {
        int m = wv * 32 + mt * 16 + quad * 4 + r;
        int bl = m >> 1, p2 = m & 1;
#pragma unroll
        for (int nt = 0; nt < 4; nt++) {
          int c = nt * 16 + l15;
          float v = fmaxf(acc[mt][nt][r] + bias[nt], 0.f);
          e2P[bl * 208 + (p2 + 1) * 64 + c] = (f16)v;
        }
      }
  }
  __syncthreads();

  {  // conv3
    f32x4 acc[4];
#pragma unroll
    for (int nt = 0; nt < 4; nt++) acc[nt] = zero4;
    const f16* aLds = &e2P[(wv * 16 + l15) * 208 + quad * 8];
    const f16* bptr = W3 + (size_t)l15 * 192 + quad * 8;
    for (int k0 = 0; k0 < 192; k0 += 32) {
      f16x8 a = *(const f16x8*)(aLds + k0);
#pragma unroll
      for (int nt = 0; nt < 4; nt++) {
        f16x8 bf = *(const f16x8*)(bptr + (size_t)nt * 16 * 192 + k0);
        acc[nt] = MFMA16(a, bf, acc[nt]);
      }
    }
    float bias[4];
#pragma unroll
    for (int nt = 0; nt < 4; nt++) bias[nt] = b3[nt * 16 + l15];
#pragma unroll
    for (int r = 0; r < 4; r++) {
      int bl = wv * 16 + quad * 4 + r;
#pragma unroll
      for (int nt = 0; nt < 4; nt++) {
        int c = nt * 16 + l15;
        e3s[bl * 64 + c] = (f16)fmaxf(acc[nt][r] + bias[nt], 0.f);
      }
    }
  }
  __syncthreads();

  {  // conv4
    f32x4 acc[8];
#pragma unroll
    for (int nt = 0; nt < 8; nt++) acc[nt] = zero4;
    const f16* aLds = &e3s[(wv * 16 + l15) * 64 + quad * 8];
    const f16* bptr = W4 + (size_t)l15 * 64 + quad * 8;
    for (int k0 = 0; k0 < 64; k0 += 32) {
      f16x8 a = *(const f16x8*)(aLds + k0);
#pragma unroll
      for (int nt = 0; nt < 8; nt++) {
        f16x8 bf = *(const f16x8*)(bptr + (size_t)nt * 16 * 64 + k0);
        acc[nt] = MFMA16(a, bf, acc[nt]);
      }
    }
    float bias[8];
#pragma unroll
    for (int nt = 0; nt < 8; nt++) bias[nt] = b4[nt * 16 + l15];
#pragma unroll
    for (int r = 0; r < 4; r++) {
      int bl = wv * 16 + quad * 4 + r;
#pragma unroll
      for (int nt = 0; nt < 8; nt++) {
        int c = nt * 16 + l15;
        gatesA[(size_t)(b0 + bl) * 256 + c] =
            (f16)fmaxf(acc[nt][r] + bias[nt], 0.f);
      }
    }
  }
}

// ---------------------------------------------------------------------------
// gates GEMM + LSTM cell + decision head.
// M=64 batch rows per block, K=256 (e4 | h0), N=512.
// Wave w covers c in [32w,32w+32): n-tiles {q*8 + 2w + u} so (i,f,g,o) for a
// given (row, c) land in the same lane/reg -> in-lane LSTM math.
// ---------------------------------------------------------------------------
__global__ __launch_bounds__(256) void gates_kernel(
    const f16* __restrict__ gatesA, const f16* __restrict__ Wg,
    const float* __restrict__ b_ih, const float* __restrict__ b_hh,
    const float* __restrict__ c0, const float* __restrict__ dec_w,
    const float* __restrict__ dec_b, float* __restrict__ out) {
  __shared__ float part[4][64];
  int tid = threadIdx.x;
  int lane = tid & 63, wv = tid >> 6;
  int l15 = lane & 15, quad = lane >> 4;
  int b0 = blockIdx.x * 64;
  f32x4 zero4 = {0.f, 0.f, 0.f, 0.f};

  float* out_h1 = out + BATCH;
  float* out_c1 = out + BATCH + (size_t)BATCH * 128;

  f32x4 acc[4][8];  // [mt][q*2+u]
#pragma unroll
  for (int mt = 0; mt < 4; mt++)
#pragma unroll
    for (int j = 0; j < 8; j++) acc[mt][j] = zero4;

  const f16* aptr[4];
#pragma unroll
  for (int mt = 0; mt < 4; mt++)
    aptr[mt] = gatesA + (size_t)(b0 + mt * 16 + l15) * 256 + quad * 8;

  const f16* bptrs[8];
#pragma unroll
  for (int q = 0; q < 4; q++)
#pragma unroll
    for (int u = 0; u < 2; u++)
      bptrs[q * 2 + u] =
          Wg + (size_t)(q * 128 + wv * 32 + u * 16 + l15) * 256 + quad * 8;

  for (int k0 = 0; k0 < 256; k0 += 32) {
    f16x8 a[4];
#pragma unroll
    for (int mt = 0; mt < 4; mt++) a[mt] = *(const f16x8*)(aptr[mt] + k0);
#pragma unroll
    for (int j = 0; j < 8; j++) {
      f16x8 bf = *(const f16x8*)(bptrs[j] + k0);
#pragma unroll
      for (int mt = 0; mt < 4; mt++) acc[mt][j] = MFMA16(a[mt], bf, acc[mt][j]);
    }
  }

  float bias[8], dw[2];
#pragma unroll
  for (int q = 0; q < 4; q++)
#pragma unroll
    for (int u = 0; u < 2; u++) {
      int n = q * 128 + wv * 32 + u * 16 + l15;
      bias[q * 2 + u] = b_ih[n] + b_hh[n];
    }
#pragma unroll
  for (int u = 0; u < 2; u++) dw[u] = dec_w[wv * 32 + u * 16 + l15];

#pragma unroll
  for (int mt = 0; mt < 4; mt++)
#pragma unroll
    for (int r = 0; r < 4; r++) {
      int bl = mt * 16 + quad * 4 + r;
      int b = b0 + bl;
      float p = 0.f;
#pragma unroll
      for (int u = 0; u < 2; u++) {
        int c = wv * 32 + u * 16 + l15;
        float iv = acc[mt][0 + u][r] + bias[0 + u];
        float fv = acc[mt][2 + u][r] + bias[2 + u];
        float gv = acc[mt][4 + u][r] + bias[4 + u];
        float ov = acc[mt][6 + u][r] + bias[6 + u];
        float c0v = c0[(size_t)b * 128 + c];
        float c1 = sigmoid_(fv) * c0v + sigmoid_(iv) * tanhf(gv);
        float h1 = sigmoid_(ov) * tanhf(c1);
        out_h1[(size_t)b * 128 + c] = h1;
        out_c1[(size_t)b * 128 + c] = c1;
        p += fmaxf(h1, 0.f) * dw[u];
      }
      p += __shfl_xor(p, 1);
      p += __shfl_xor(p, 2);
      p += __shfl_xor(p, 4);
      p += __shfl_xor(p, 8);
      if (l15 == 0) part[wv][bl] = p;
    }
  __syncthreads();
  if (tid < 64) {
    float s = part[0][tid] + part[1][tid] + part[2][tid] + part[3][tid] +
              dec_b[0];
    out[b0 + tid] = 1.f / (1.f + __expf(-s));
  }
}

// ---------------------------------------------------------------------------
extern "C" void kernel_launch(void* const* d_in, const int* in_sizes, int n_in,
                              void* d_out, int out_size, void* d_ws,
                              size_t ws_size, hipStream_t stream) {
  const float* x = (const float*)d_in[0];
  const float* h0 = (const float*)d_in[1];
  const float* c0 = (const float*)d_in[2];
  const float* basis = (const float*)d_in[3];
  const float* w1 = (const float*)d_in[4];
  const float* b1 = (const float*)d_in[5];
  const float* w2 = (const float*)d_in[6];
  const float* b2 = (const float*)d_in[7];
  const float* w3 = (const float*)d_in[8];
  const float* b3 = (const float*)d_in[9];
  const float* w4 = (const float*)d_in[10];
  const float* b4 = (const float*)d_in[11];
  const float* w_ih = (const float*)d_in[12];
  const float* w_hh = (const float*)d_in[13];
  const float* b_ih = (const float*)d_in[14];
  const float* b_hh = (const float*)d_in[15];
  const float* dec_w = (const float*)d_in[16];
  const float* dec_b = (const float*)d_in[17];

  char* ws = (char*)d_ws;
  f16* xp = (f16*)(ws + OFF_XP);
  f16* e1P = (f16*)(ws + OFF_XP);  // aliases xp (dead after stft)
  f16* magP = (f16*)(ws + OFF_MAGP);
  f16* gatesA = (f16*)(ws + OFF_GATESA);
  f16* Bf = (f16*)(ws + OFF_BF);
  f16* W1 = (f16*)(ws + OFF_W1);
  f16* W2 = (f16*)(ws + OFF_W2);
  f16* W3 = (f16*)(ws + OFF_W3);
  f16* W4 = (f16*)(ws + OFF_W4);
  f16* Wg = (f16*)(ws + OFF_WG);

  prep_kernel<<<1088, 256, 0, stream>>>(x, h0, basis, w1, w2, w3, w4, w_ih,
                                        w_hh, xp, magP, gatesA, Bf, W1, W2, W3,
                                        W4, Wg);
  stft_kernel<<<4096, 64, 0, stream>>>(xp, Bf, magP);
  conv1_kernel<<<512, 256, 0, stream>>>(magP, W1, b1, e1P);
  c234_kernel<<<512, 256, 0, stream>>>(e1P, W2, b2, W3, b3, W4, b4, gatesA);
  gates_kernel<<<512, 256, 0, stream>>>(gatesA, Wg, b_ih, b_hh, c0, dec_w,
                                        dec_b, (float*)d_out);
}

// Round 2
// 387.923 us; speedup vs baseline: 1.2592x; 1.2592x over previous
//
#include <hip/hip_runtime.h>

typedef _Float16 f16;
typedef _Float16 f16x8 __attribute__((ext_vector_type(8)));
typedef _Float16 f16x4 __attribute__((ext_vector_type(4)));
typedef float f32x4 __attribute__((ext_vector_type(4)));

#define MFMA16(a, b, c) __builtin_amdgcn_mfma_f32_16x16x32_f16((a), (b), (c), 0, 0, 0)

#define BATCH 32768

// workspace layout (bytes)
#define OFF_XP      ((size_t)0)                    // xp: B*704 f16 (reused as e1P: B*640 f16)
#define OFF_MAGP    ((size_t)46137344)             // magP: B*832 f16
#define OFF_GATESA  ((size_t)(46137344 + 54525952))// gatesA: B*256 f16
#define OFF_BF      (OFF_GATESA + 16777216)        // Bf2 [8][272][32] f16 = 139,264
#define OFF_W1      (OFF_BF + 139264)              // W1i [13][128][32] f16 = 106,496
#define OFF_W2      (OFF_W1 + 106496)              // [64][384]
#define OFF_W3      (OFF_W2 + 49152)               // [64][192]
#define OFF_W4      (OFF_W3 + 24576)               // [128][64]
#define OFF_WG      (OFF_W4 + 16384)               // [512][256]

__device__ __forceinline__ float sigmoid_(float x) { return 1.f / (1.f + __expf(-x)); }

// ---------------------------------------------------------------------------
// prep: build xp (reflect-padded signal, vectorized), zero magP pad positions,
// write h0 into gatesA[:,128:256], and cast/transpose weights into GEMM
// layouts (basis & W1 k-interleaved for L1 residency).
// ---------------------------------------------------------------------------
__global__ __launch_bounds__(256) void prep_kernel(
    const float* __restrict__ x, const float* __restrict__ h0,
    const float* __restrict__ basis, const float* __restrict__ w1,
    const float* __restrict__ w2, const float* __restrict__ w3,
    const float* __restrict__ w4, const float* __restrict__ w_ih,
    const float* __restrict__ w_hh,
    f16* __restrict__ xp, f16* __restrict__ magP, f16* __restrict__ gatesA,
    f16* __restrict__ Bf2, f16* __restrict__ W1i, f16* __restrict__ W2,
    f16* __restrict__ W3, f16* __restrict__ W4, f16* __restrict__ Wg) {
  int blk = blockIdx.x;
  int tid = threadIdx.x;
  if (blk < 1024) {
    int b0 = blk * 32;
    // xp[b][4g..4g+4), g in [0,176)
    for (int idx = tid; idx < 32 * 176; idx += 256) {
      int bl = idx / 176, g = idx - bl * 176;
      int b = b0 + bl;
      f16x4 o;
      if (g < 32) {
        float v0 = (g == 0) ? x[(size_t)b * 512] : 0.f;
        o = (f16x4){(f16)v0, (f16)0.f, (f16)0.f, (f16)0.f};
      } else if (g < 160) {
        const float4 v = *(const float4*)(x + (size_t)b * 512 + 4 * g - 128);
        o = (f16x4){(f16)v.x, (f16)v.y, (f16)v.z, (f16)v.w};
      } else {
        int j0 = 4 * g;  // [640,704)
        const float* xb = x + (size_t)b * 512;
        o = (f16x4){(f16)xb[1150 - j0], (f16)xb[1149 - j0], (f16)xb[1148 - j0],
                    (f16)xb[1147 - j0]};
      }
      *(f16x4*)(xp + (size_t)b * 704 + 4 * g) = o;
    }
    // magP zero pads: [0,136) = 17 groups, [680,832) = 19 groups (f16x8)
    f16x8 z8 = {};
    for (int idx = tid; idx < 32 * 36; idx += 256) {
      int bl = idx / 36, g = idx - bl * 36;
      int off = (g < 17) ? g * 8 : 680 + (g - 17) * 8;
      *(f16x8*)(magP + (size_t)(b0 + bl) * 832 + off) = z8;
    }
    // gatesA[:,128:256) = f16(h0)
    for (int idx = tid; idx < 32 * 32; idx += 256) {
      int bl = idx >> 5, g = idx & 31;
      const float4 v = *(const float4*)(h0 + (size_t)(b0 + bl) * 128 + g * 4);
      f16x4 o = {(f16)v.x, (f16)v.y, (f16)v.z, (f16)v.w};
      *(f16x4*)(gatesA + (size_t)(b0 + bl) * 256 + 128 + g * 4) = o;
    }
  } else {
    int t = (blk - 1024) * 256 + tid;  // 0..16383
    // basis -> Bf2[kb][n][kk], n>=258 zero
    for (int idx = t; idx < 8 * 272 * 32; idx += 16384) {
      int kb = idx / 8704, rest = idx - kb * 8704;
      int n = rest >> 5, kk = rest & 31;
      Bf2[idx] = (f16)((n < 258) ? basis[n * 256 + kb * 32 + kk] : 0.f);
    }
    // w1 (128,129,3) -> W1i[kb][n][kk], logical k = tap*136 + i, K=416
    for (int idx = t; idx < 13 * 128 * 32; idx += 16384) {
      int kb = idx / 4096, rest = idx - kb * 4096;
      int n = rest >> 5, kk = rest & 31;
      int k = kb * 32 + kk;
      int tap = k / 136, i = k - tap * 136;
      float v = (tap < 3 && i < 129) ? w1[(n * 129 + i) * 3 + tap] : 0.f;
      W1i[idx] = (f16)v;
    }
    // w2 (64,128,3) -> W2[n][k], k = tap*128 + i, K=384
    for (int idx = t; idx < 64 * 384; idx += 16384) {
      int n = idx / 384, k = idx - n * 384;
      int tap = k >> 7, i = k & 127;
      W2[idx] = (f16)w2[(n * 128 + i) * 3 + tap];
    }
    // w3 (64,64,3) -> W3[n][k], k = tap*64 + i, K=192
    for (int idx = t; idx < 64 * 192; idx += 16384) {
      int n = idx / 192, k = idx - n * 192;
      int tap = k >> 6, i = k & 63;
      W3[idx] = (f16)w3[(n * 64 + i) * 3 + tap];
    }
    // w4 (128,64,3), only tap=1 contributes -> W4[n][i], K=64
    for (int idx = t; idx < 128 * 64; idx += 16384) {
      int n = idx >> 6, i = idx & 63;
      W4[idx] = (f16)w4[(n * 64 + i) * 3 + 1];
    }
    // Wg[512][256] = [w_ih | w_hh]
    for (int idx = t; idx < 512 * 256; idx += 16384) {
      int n = idx >> 8, k = idx & 255;
      Wg[idx] = (f16)((k < 128) ? w_ih[n * 128 + k] : w_hh[n * 128 + (k - 128)]);
    }
  }
}

// ---------------------------------------------------------------------------
// STFT GEMM + magnitude epilogue (no LDS).
// 4 waves/block, wave tile M=32 x N=272 (17 n-tiles). m = b*4 + t.
// Bf2 is k-interleaved [kb][272 n][32 kk] -> per k-step footprint 17.4 KB
// (L1-resident, shared by the block's 4 waves).
// Epilogue: mag[c] = sqrt(ft[c]^2 + ft[c+129]^2); ft[c+129] fetched via
// in-wave shfl from tile nt+8 (lane l15+1) or nt+9 (lane 0) for l15==15.
// ---------------------------------------------------------------------------
__global__ __launch_bounds__(256) void stft_kernel(
    const f16* __restrict__ xp, const f16* __restrict__ Bf2,
    f16* __restrict__ magP) {
  int tid = threadIdx.x;
  int lane = tid & 63, wv = tid >> 6;
  int l15 = lane & 15, quad = lane >> 4;
  int m0 = blockIdx.x * 128 + wv * 32;

  f32x4 zero4 = {0.f, 0.f, 0.f, 0.f};
  f32x4 acc[2][17];
#pragma unroll
  for (int mt = 0; mt < 2; mt++)
#pragma unroll
    for (int nt = 0; nt < 17; nt++) acc[mt][nt] = zero4;

  const f16* aptr[2];
#pragma unroll
  for (int mt = 0; mt < 2; mt++) {
    int m = m0 + mt * 16 + l15;
    int b = m >> 2, t = m & 3;
    aptr[mt] = xp + (size_t)b * 704 + t * 128 + quad * 8;
  }
  const f16* bbase = Bf2 + l15 * 32 + quad * 8;

  for (int kb = 0; kb < 8; kb++) {
    f16x8 a0 = *(const f16x8*)(aptr[0] + kb * 32);
    f16x8 a1 = *(const f16x8*)(aptr[1] + kb * 32);
    const f16* bp = bbase + kb * 8704;
#pragma unroll
    for (int nt = 0; nt < 17; nt++) {
      f16x8 bf = *(const f16x8*)(bp + nt * 512);
      acc[0][nt] = MFMA16(a0, bf, acc[0][nt]);
      acc[1][nt] = MFMA16(a1, bf, acc[1][nt]);
    }
  }

  // epilogue: row m = m0 + mt*16 + quad*4 + r  ->  b = m0/4 + mt*4 + quad, t=r
#pragma unroll
  for (int mt = 0; mt < 2; mt++) {
#pragma unroll
    for (int r = 0; r < 4; r++) {
      int b = (m0 >> 2) + mt * 4 + quad;
      f16* orow = magP + (size_t)b * 832 + (r + 1) * 136;
#pragma unroll
      for (int nt = 0; nt < 9; nt++) {
        float re = acc[mt][nt][r];
        float imA = __shfl(acc[mt][nt + 8][r], (quad << 4) | ((l15 + 1) & 15), 64);
        float im;
        if (nt < 8) {
          float imB = __shfl(acc[mt][nt + 9][r], quad << 4, 64);
          im = (l15 == 15) ? imB : imA;
        } else {
          im = imA;  // nt==8: only l15==0 stores, uses imA path
        }
        int c = nt * 16 + l15;
        if (c <= 128) orow[c] = (f16)sqrtf(re * re + im * im);
      }
    }
  }
}

// ---------------------------------------------------------------------------
// conv1 GEMM: M' = 4*B rows (m = b*4 + p), A row = magP[b] + p*136, K=416,
// N=128. Wave tile M=64 x N=128. W1i k-interleaved [kb][128][32].
// Epilogue: +bias, relu -> e1P position p+1; zero e1P position 0.
// ---------------------------------------------------------------------------
__global__ __launch_bounds__(256) void conv1_kernel(
    const f16* __restrict__ magP, const f16* __restrict__ W1i,
    const float* __restrict__ b1, f16* __restrict__ e1P) {
  int lane = threadIdx.x & 63, wv = threadIdx.x >> 6;
  int l15 = lane & 15, quad = lane >> 4;
  int m0 = (blockIdx.x * 4 + wv) * 64;

  f32x4 zero4 = {0.f, 0.f, 0.f, 0.f};
  f32x4 acc[4][8];
#pragma unroll
  for (int mt = 0; mt < 4; mt++)
#pragma unroll
    for (int nt = 0; nt < 8; nt++) acc[mt][nt] = zero4;

  const f16* aptr[4];
#pragma unroll
  for (int mt = 0; mt < 4; mt++) {
    int m = m0 + mt * 16 + l15;
    int b = m >> 2, p = m & 3;
    aptr[mt] = magP + (size_t)b * 832 + p * 136 + quad * 8;
  }
  const f16* bbase = W1i + l15 * 32 + quad * 8;

  for (int kb = 0; kb < 13; kb++) {
    f16x8 a[4];
#pragma unroll
    for (int mt = 0; mt < 4; mt++) a[mt] = *(const f16x8*)(aptr[mt] + kb * 32);
    const f16* bp = bbase + kb * 4096;
#pragma unroll
    for (int nt = 0; nt < 8; nt++) {
      f16x8 bf = *(const f16x8*)(bp + nt * 512);
#pragma unroll
      for (int mt = 0; mt < 4; mt++) acc[mt][nt] = MFMA16(a[mt], bf, acc[mt][nt]);
    }
  }

  float bias[8];
#pragma unroll
  for (int nt = 0; nt < 8; nt++) bias[nt] = b1[nt * 16 + l15];

#pragma unroll
  for (int mt = 0; mt < 4; mt++)
#pragma unroll
    for (int r = 0; r < 4; r++) {
      int m = m0 + mt * 16 + quad * 4 + r;
      int b = m >> 2, p = m & 3;
#pragma unroll
      for (int nt = 0; nt < 8; nt++) {
        int c = nt * 16 + l15;
        float v = fmaxf(acc[mt][nt][r] + bias[nt], 0.f);
        e1P[(size_t)b * 640 + (p + 1) * 128 + c] = (f16)v;
        if (p == 0) e1P[(size_t)b * 640 + c] = (f16)0.f;  // zero pad position
      }
    }
}

// ---------------------------------------------------------------------------
// c234: conv2 -> conv3 -> conv4 fused; 64 batch rows per block (4 waves).
// ---------------------------------------------------------------------------
__global__ __launch_bounds__(256) void c234_kernel(
    const f16* __restrict__ e1P, const f16* __restrict__ W2,
    const float* __restrict__ b2, const f16* __restrict__ W3,
    const float* __restrict__ b3, const f16* __restrict__ W4,
    const float* __restrict__ b4, f16* __restrict__ gatesA) {
  __shared__ __align__(16) f16 e2P[64 * 208];
  __shared__ __align__(16) f16 e3s[64 * 64];
  int tid = threadIdx.x;
  int lane = tid & 63, wv = tid >> 6;
  int l15 = lane & 15, quad = lane >> 4;
  int b0 = blockIdx.x * 64;
  f32x4 zero4 = {0.f, 0.f, 0.f, 0.f};

  // zero e2P storage position 0 (conv3's position -1)
  for (int i = tid; i < 64 * 64; i += 256) {
    int bl = i >> 6, c = i & 63;
    e2P[bl * 208 + c] = (f16)0.f;
  }
  __syncthreads();

  {  // conv2
    f32x4 acc[2][4];
#pragma unroll
    for (int mt = 0; mt < 2; mt++)
#pragma unroll
      for (int nt = 0; nt < 4; nt++) acc[mt][nt] = zero4;
    const f16* aptr[2];
#pragma unroll
    for (int mt = 0; mt < 2; mt++) {
      int m = wv * 32 + mt * 16 + l15;
      int bl = m >> 1, p2 = m & 1;
      aptr[mt] = e1P + (size_t)(b0 + bl) * 640 + p2 * 256 + quad * 8;
    }
    const f16* bptr = W2 + (size_t)l15 * 384 + quad * 8;
    for (int k0 = 0; k0 < 384; k0 += 32) {
      f16x8 a0 = *(const f16x8*)(aptr[0] + k0);
      f16x8 a1 = *(const f16x8*)(aptr[1] + k0);
#pragma unroll
      for (int nt = 0; nt < 4; nt++) {
        f16x8 bf = *(const f16x8*)(bptr + (size_t)nt * 16 * 384 + k0);
        acc[0][nt] = MFMA16(a0, bf, acc[0][nt]);
        acc[1][nt] = MFMA16(a1, bf, acc[1][nt]);
      }
    }
    float bias[4];
#pragma unroll
    for (int nt = 0; nt < 4; nt++) bias[nt] = b2[nt * 16 + l15];
#pragma unroll
    for (int mt = 0; mt < 2; mt++)
#pragma unroll
      for (int r = 0; r < 4; r++) {
        int m = wv * 32 + mt * 16 + quad * 4 + r;
        int bl = m >> 1, p2 = m & 1;
#pragma unroll
        for (int nt = 0; nt < 4; nt++) {
          int c = nt * 16 + l15;
          float v = fmaxf(acc[mt][nt][r] + bias[nt], 0.f);
          e2P[bl * 208 + (p2 + 1) * 64 + c] = (f16)v;
        }
      }
  }
  __syncthreads();

  {  // conv3
    f32x4 acc[4];
#pragma unroll
    for (int nt = 0; nt < 4; nt++) acc[nt] = zero4;
    const f16* aLds = &e2P[(wv * 16 + l15) * 208 + quad * 8];
    const f16* bptr = W3 + (size_t)l15 * 192 + quad * 8;
    for (int k0 = 0; k0 < 192; k0 += 32) {
      f16x8 a = *(const f16x8*)(aLds + k0);
#pragma unroll
      for (int nt = 0; nt < 4; nt++) {
        f16x8 bf = *(const f16x8*)(bptr + (size_t)nt * 16 * 192 + k0);
        acc[nt] = MFMA16(a, bf, acc[nt]);
      }
    }
    float bias[4];
#pragma unroll
    for (int nt = 0; nt < 4; nt++) bias[nt] = b3[nt * 16 + l15];
#pragma unroll
    for (int r = 0; r < 4; r++) {
      int bl = wv * 16 + quad * 4 + r;
#pragma unroll
      for (int nt = 0; nt < 4; nt++) {
        int c = nt * 16 + l15;
        e3s[bl * 64 + c] = (f16)fmaxf(acc[nt][r] + bias[nt], 0.f);
      }
    }
  }
  __syncthreads();

  {  // conv4
    f32x4 acc[8];
#pragma unroll
    for (int nt = 0; nt < 8; nt++) acc[nt] = zero4;
    const f16* aLds = &e3s[(wv * 16 + l15) * 64 + quad * 8];
    const f16* bptr = W4 + (size_t)l15 * 64 + quad * 8;
    for (int k0 = 0; k0 < 64; k0 += 32) {
      f16x8 a = *(const f16x8*)(aLds + k0);
#pragma unroll
      for (int nt = 0; nt < 8; nt++) {
        f16x8 bf = *(const f16x8*)(bptr + (size_t)nt * 16 * 64 + k0);
        acc[nt] = MFMA16(a, bf, acc[nt]);
      }
    }
    float bias[8];
#pragma unroll
    for (int nt = 0; nt < 8; nt++) bias[nt] = b4[nt * 16 + l15];
#pragma unroll
    for (int r = 0; r < 4; r++) {
      int bl = wv * 16 + quad * 4 + r;
#pragma unroll
      for (int nt = 0; nt < 8; nt++) {
        int c = nt * 16 + l15;
        gatesA[(size_t)(b0 + bl) * 256 + c] =
            (f16)fmaxf(acc[nt][r] + bias[nt], 0.f);
      }
    }
  }
}

// ---------------------------------------------------------------------------
// gates GEMM + LSTM cell + decision head.
// ---------------------------------------------------------------------------
__global__ __launch_bounds__(256) void gates_kernel(
    const f16* __restrict__ gatesA, const f16* __restrict__ Wg,
    const float* __restrict__ b_ih, const float* __restrict__ b_hh,
    const float* __restrict__ c0, const float* __restrict__ dec_w,
    const float* __restrict__ dec_b, float* __restrict__ out) {
  __shared__ float part[4][64];
  int tid = threadIdx.x;
  int lane = tid & 63, wv = tid >> 6;
  int l15 = lane & 15, quad = lane >> 4;
  int b0 = blockIdx.x * 64;
  f32x4 zero4 = {0.f, 0.f, 0.f, 0.f};

  float* out_h1 = out + BATCH;
  float* out_c1 = out + BATCH + (size_t)BATCH * 128;

  f32x4 acc[4][8];  // [mt][q*2+u]
#pragma unroll
  for (int mt = 0; mt < 4; mt++)
#pragma unroll
    for (int j = 0; j < 8; j++) acc[mt][j] = zero4;

  const f16* aptr[4];
#pragma unroll
  for (int mt = 0; mt < 4; mt++)
    aptr[mt] = gatesA + (size_t)(b0 + mt * 16 + l15) * 256 + quad * 8;

  const f16* bptrs[8];
#pragma unroll
  for (int q = 0; q < 4; q++)
#pragma unroll
    for (int u = 0; u < 2; u++)
      bptrs[q * 2 + u] =
          Wg + (size_t)(q * 128 + wv * 32 + u * 16 + l15) * 256 + quad * 8;

  for (int k0 = 0; k0 < 256; k0 += 32) {
    f16x8 a[4];
#pragma unroll
    for (int mt = 0; mt < 4; mt++) a[mt] = *(const f16x8*)(aptr[mt] + k0);
#pragma unroll
    for (int j = 0; j < 8; j++) {
      f16x8 bf = *(const f16x8*)(bptrs[j] + k0);
#pragma unroll
      for (int mt = 0; mt < 4; mt++) acc[mt][j] = MFMA16(a[mt], bf, acc[mt][j]);
    }
  }

  float bias[8], dw[2];
#pragma unroll
  for (int q = 0; q < 4; q++)
#pragma unroll
    for (int u = 0; u < 2; u++) {
      int n = q * 128 + wv * 32 + u * 16 + l15;
      bias[q * 2 + u] = b_ih[n] + b_hh[n];
    }
#pragma unroll
  for (int u = 0; u < 2; u++) dw[u] = dec_w[wv * 32 + u * 16 + l15];

#pragma unroll
  for (int mt = 0; mt < 4; mt++)
#pragma unroll
    for (int r = 0; r < 4; r++) {
      int bl = mt * 16 + quad * 4 + r;
      int b = b0 + bl;
      float p = 0.f;
#pragma unroll
      for (int u = 0; u < 2; u++) {
        int c = wv * 32 + u * 16 + l15;
        float iv = acc[mt][0 + u][r] + bias[0 + u];
        float fv = acc[mt][2 + u][r] + bias[2 + u];
        float gv = acc[mt][4 + u][r] + bias[4 + u];
        float ov = acc[mt][6 + u][r] + bias[6 + u];
        float c0v = c0[(size_t)b * 128 + c];
        float c1 = sigmoid_(fv) * c0v + sigmoid_(iv) * tanhf(gv);
        float h1 = sigmoid_(ov) * tanhf(c1);
        out_h1[(size_t)b * 128 + c] = h1;
        out_c1[(size_t)b * 128 + c] = c1;
        p += fmaxf(h1, 0.f) * dw[u];
      }
      p += __shfl_xor(p, 1);
      p += __shfl_xor(p, 2);
      p += __shfl_xor(p, 4);
      p += __shfl_xor(p, 8);
      if (l15 == 0) part[wv][bl] = p;
    }
  __syncthreads();
  if (tid < 64) {
    float s = part[0][tid] + part[1][tid] + part[2][tid] + part[3][tid] +
              dec_b[0];
    out[b0 + tid] = 1.f / (1.f + __expf(-s));
  }
}

// ---------------------------------------------------------------------------
extern "C" void kernel_launch(void* const* d_in, const int* in_sizes, int n_in,
                              void* d_out, int out_size, void* d_ws,
                              size_t ws_size, hipStream_t stream) {
  const float* x = (const float*)d_in[0];
  const float* h0 = (const float*)d_in[1];
  const float* c0 = (const float*)d_in[2];
  const float* basis = (const float*)d_in[3];
  const float* w1 = (const float*)d_in[4];
  const float* b1 = (const float*)d_in[5];
  const float* w2 = (const float*)d_in[6];
  const float* b2 = (const float*)d_in[7];
  const float* w3 = (const float*)d_in[8];
  const float* b3 = (const float*)d_in[9];
  const float* w4 = (const float*)d_in[10];
  const float* b4 = (const float*)d_in[11];
  const float* w_ih = (const float*)d_in[12];
  const float* w_hh = (const float*)d_in[13];
  const float* b_ih = (const float*)d_in[14];
  const float* b_hh = (const float*)d_in[15];
  const float* dec_w = (const float*)d_in[16];
  const float* dec_b = (const float*)d_in[17];

  char* ws = (char*)d_ws;
  f16* xp = (f16*)(ws + OFF_XP);
  f16* e1P = (f16*)(ws + OFF_XP);  // aliases xp (dead after stft)
  f16* magP = (f16*)(ws + OFF_MAGP);
  f16* gatesA = (f16*)(ws + OFF_GATESA);
  f16* Bf2 = (f16*)(ws + OFF_BF);
  f16* W1i = (f16*)(ws + OFF_W1);
  f16* W2 = (f16*)(ws + OFF_W2);
  f16* W3 = (f16*)(ws + OFF_W3);
  f16* W4 = (f16*)(ws + OFF_W4);
  f16* Wg = (f16*)(ws + OFF_WG);

  prep_kernel<<<1088, 256, 0, stream>>>(x, h0, basis, w1, w2, w3, w4, w_ih,
                                        w_hh, xp, magP, gatesA, Bf2, W1i, W2,
                                        W3, W4, Wg);
  stft_kernel<<<1024, 256, 0, stream>>>(xp, Bf2, magP);
  conv1_kernel<<<512, 256, 0, stream>>>(magP, W1i, b1, e1P);
  c234_kernel<<<512, 256, 0, stream>>>(e1P, W2, b2, W3, b3, W4, b4, gatesA);
  gates_kernel<<<512, 256, 0, stream>>>(gatesA, Wg, b_ih, b_hh, c0, dec_w,
                                        dec_b, (float*)d_out);
}

// Round 3
// 359.084 us; speedup vs baseline: 1.3603x; 1.0803x over previous
//
#include <hip/hip_runtime.h>

typedef _Float16 f16;
typedef _Float16 f16x8 __attribute__((ext_vector_type(8)));
typedef _Float16 f16x4 __attribute__((ext_vector_type(4)));
typedef float f32x4 __attribute__((ext_vector_type(4)));

#define MFMA16(a, b, c) __builtin_amdgcn_mfma_f32_16x16x32_f16((a), (b), (c), 0, 0, 0)

#define BATCH 32768

// workspace layout (bytes)
#define OFF_XP      ((size_t)0)                    // xp: B*704 f16
#define OFF_MAGP    ((size_t)46137344)             // magP: B*832 f16
#define OFF_BF      (OFF_MAGP + 54525952)          // Bf3 frag-major [8][17][64][8] f16 = 139,264
#define OFF_W1      (OFF_BF + 139264)              // W1i [13][128][32] f16 = 106,496
#define OFF_W2      (OFF_W1 + 106496)              // [64][384]
#define OFF_W3      (OFF_W2 + 49152)               // [64][192]
#define OFF_W4      (OFF_W3 + 24576)               // [128][64]
#define OFF_WG      (OFF_W4 + 16384)               // [512][256]

__device__ __forceinline__ float sigmoid_(float x) { return 1.f / (1.f + __expf(-x)); }

// ---------------------------------------------------------------------------
// prep: xp (reflect-padded signal), magP pad zeroing, weight repacks.
// Bf3 is frag-major: chunk (kb, tile) = 1024B; within chunk element order =
// lane-linear (lane = quad*16+l15 holds n=tile*16+l15, k=kb*32+quad*8+jj).
// ---------------------------------------------------------------------------
__global__ __launch_bounds__(256) void prep_kernel(
    const float* __restrict__ x, const float* __restrict__ basis,
    const float* __restrict__ w1, const float* __restrict__ w2,
    const float* __restrict__ w3, const float* __restrict__ w4,
    const float* __restrict__ w_ih, const float* __restrict__ w_hh,
    f16* __restrict__ xp, f16* __restrict__ magP,
    f16* __restrict__ Bf3, f16* __restrict__ W1i, f16* __restrict__ W2,
    f16* __restrict__ W3, f16* __restrict__ W4, f16* __restrict__ Wg) {
  int blk = blockIdx.x;
  int tid = threadIdx.x;
  if (blk < 1024) {
    int b0 = blk * 32;
    // xp[b][4g..4g+4), g in [0,176)
    for (int idx = tid; idx < 32 * 176; idx += 256) {
      int bl = idx / 176, g = idx - bl * 176;
      int b = b0 + bl;
      f16x4 o;
      if (g < 32) {
        float v0 = (g == 0) ? x[(size_t)b * 512] : 0.f;
        o = (f16x4){(f16)v0, (f16)0.f, (f16)0.f, (f16)0.f};
      } else if (g < 160) {
        const float4 v = *(const float4*)(x + (size_t)b * 512 + 4 * g - 128);
        o = (f16x4){(f16)v.x, (f16)v.y, (f16)v.z, (f16)v.w};
      } else {
        int j0 = 4 * g;  // [640,704)
        const float* xb = x + (size_t)b * 512;
        o = (f16x4){(f16)xb[1150 - j0], (f16)xb[1149 - j0], (f16)xb[1148 - j0],
                    (f16)xb[1147 - j0]};
      }
      *(f16x4*)(xp + (size_t)b * 704 + 4 * g) = o;
    }
    // magP zero pads: [0,136) = 17 groups, [680,832) = 19 groups (f16x8)
    f16x8 z8 = {};
    for (int idx = tid; idx < 32 * 36; idx += 256) {
      int bl = idx / 36, g = idx - bl * 36;
      int off = (g < 17) ? g * 8 : 680 + (g - 17) * 8;
      *(f16x8*)(magP + (size_t)(b0 + bl) * 832 + off) = z8;
    }
  } else {
    int t = (blk - 1024) * 256 + tid;  // 0..16383
    // basis -> Bf3 frag-major
    for (int idx = t; idx < 8 * 17 * 512; idx += 16384) {
      int jj = idx & 7;
      int lane = (idx >> 3) & 63;
      int rest = idx >> 9;
      int tt = rest % 17, kb = rest / 17;
      int n = tt * 16 + (lane & 15);
      int k = kb * 32 + (lane >> 4) * 8 + jj;
      Bf3[idx] = (f16)((n < 258) ? basis[n * 256 + k] : 0.f);
    }
    // w1 (128,129,3) -> W1i[kb][n][kk], logical k = tap*136 + i, K=416
    for (int idx = t; idx < 13 * 128 * 32; idx += 16384) {
      int kb = idx / 4096, rest = idx - kb * 4096;
      int n = rest >> 5, kk = rest & 31;
      int k = kb * 32 + kk;
      int tap = k / 136, i = k - tap * 136;
      float v = (tap < 3 && i < 129) ? w1[(n * 129 + i) * 3 + tap] : 0.f;
      W1i[idx] = (f16)v;
    }
    // w2 (64,128,3) -> W2[n][k], k = tap*128 + i, K=384
    for (int idx = t; idx < 64 * 384; idx += 16384) {
      int n = idx / 384, k = idx - n * 384;
      int tap = k >> 7, i = k & 127;
      W2[idx] = (f16)w2[(n * 128 + i) * 3 + tap];
    }
    // w3 (64,64,3) -> W3[n][k], k = tap*64 + i, K=192
    for (int idx = t; idx < 64 * 192; idx += 16384) {
      int n = idx / 192, k = idx - n * 192;
      int tap = k >> 6, i = k & 63;
      W3[idx] = (f16)w3[(n * 64 + i) * 3 + tap];
    }
    // w4 (128,64,3), only tap=1 contributes -> W4[n][i], K=64
    for (int idx = t; idx < 128 * 64; idx += 16384) {
      int n = idx >> 6, i = idx & 63;
      W4[idx] = (f16)w4[(n * 64 + i) * 3 + 1];
    }
    // Wg[512][256] = [w_ih | w_hh]
    for (int idx = t; idx < 512 * 256; idx += 16384) {
      int n = idx >> 8, k = idx & 255;
      Wg[idx] = (f16)((k < 128) ? w_ih[n * 128 + k] : w_hh[n * 128 + (k - 128)]);
    }
  }
}

// ---------------------------------------------------------------------------
// STFT v4: LDS-slab double-buffered GEMM + in-wave magnitude epilogue.
// Block = 4 waves, M_block = 64 rows (16 b), all waves share M, split N:
// wave w owns tiles {2w, 2w+1, 2w+8, 2w+9} (+ tile16 for w0).
// Slab (17 tiles x 1024B) staged per kb via regs; frag-major layout makes
// both stage-write and frag-read lane-linear (conflict-free).
// ---------------------------------------------------------------------------
__global__ __launch_bounds__(256) void stft_kernel(
    const f16* __restrict__ xp, const f16* __restrict__ Bf3,
    f16* __restrict__ magP) {
  __shared__ __align__(16) f16 Bslab[2][17 * 512];
  __shared__ float imPatch[4][64];
  int tid = threadIdx.x;
  int lane = tid & 63, wv = tid >> 6;
  int l15 = lane & 15, quad = lane >> 4;
  int m0 = blockIdx.x * 64;

  int t0 = 2 * wv, t1 = 2 * wv + 1, t2 = 2 * wv + 8, t3 = 2 * wv + 9;

  f32x4 zero4 = {0.f, 0.f, 0.f, 0.f};
  f32x4 acc[4][4];  // [slot][mt]
  f32x4 acc4[4];    // tile16 (wave0 only)
#pragma unroll
  for (int s = 0; s < 4; s++)
#pragma unroll
    for (int mt = 0; mt < 4; mt++) acc[s][mt] = zero4;
#pragma unroll
  for (int mt = 0; mt < 4; mt++) acc4[mt] = zero4;

  const f16* aptr[4];
#pragma unroll
  for (int mt = 0; mt < 4; mt++) {
    int m = m0 + mt * 16 + l15;
    int b = m >> 2, t = m & 3;
    aptr[mt] = xp + (size_t)b * 704 + t * 128 + quad * 8;
  }

  // prologue: stage kb=0 into buffer 0
  f16x8 stg[5];
#pragma unroll
  for (int i = 0; i < 5; i++) {
    int j = wv + 4 * i;
    if (j < 17) stg[i] = *(const f16x8*)(Bf3 + (size_t)j * 512 + lane * 8);
  }
#pragma unroll
  for (int i = 0; i < 5; i++) {
    int j = wv + 4 * i;
    if (j < 17) *(f16x8*)&Bslab[0][j * 512 + lane * 8] = stg[i];
  }

  for (int kb = 0; kb < 8; kb++) {
    __syncthreads();  // publishes buffer kb&1
    int cur = kb & 1;
    if (kb < 7) {
#pragma unroll
      for (int i = 0; i < 5; i++) {
        int j = wv + 4 * i;
        if (j < 17)
          stg[i] = *(const f16x8*)(Bf3 + ((size_t)(kb + 1) * 17 + j) * 512 +
                                   lane * 8);
      }
    }
    f16x8 a[4];
#pragma unroll
    for (int mt = 0; mt < 4; mt++) a[mt] = *(const f16x8*)(aptr[mt] + kb * 32);
    {
      f16x8 b0f = *(const f16x8*)&Bslab[cur][t0 * 512 + lane * 8];
      f16x8 b1f = *(const f16x8*)&Bslab[cur][t1 * 512 + lane * 8];
      f16x8 b2f = *(const f16x8*)&Bslab[cur][t2 * 512 + lane * 8];
      f16x8 b3f = *(const f16x8*)&Bslab[cur][t3 * 512 + lane * 8];
#pragma unroll
      for (int mt = 0; mt < 4; mt++) {
        acc[0][mt] = MFMA16(a[mt], b0f, acc[0][mt]);
        acc[1][mt] = MFMA16(a[mt], b1f, acc[1][mt]);
        acc[2][mt] = MFMA16(a[mt], b2f, acc[2][mt]);
        acc[3][mt] = MFMA16(a[mt], b3f, acc[3][mt]);
      }
      if (wv == 0) {
        f16x8 b4f = *(const f16x8*)&Bslab[cur][16 * 512 + lane * 8];
#pragma unroll
        for (int mt = 0; mt < 4; mt++) acc4[mt] = MFMA16(a[mt], b4f, acc4[mt]);
      }
    }
    if (kb < 7) {
#pragma unroll
      for (int i = 0; i < 5; i++) {
        int j = wv + 4 * i;
        if (j < 17) *(f16x8*)&Bslab[cur ^ 1][j * 512 + lane * 8] = stg[i];
      }
    }
  }

  // epilogue: patch for the 4 cross-wave boundary columns
  // wave w's broken col c=32w+31 needs tile 2w+10 lane0 -> imPatch[w].
  // writer: wave v writes its tile (2v+8) [v>=1] to imPatch[v-1];
  //         wave 0 writes tile16 to imPatch[3].
  __syncthreads();
  {
    int dst = (wv == 0) ? 3 : (wv - 1);
    if (l15 == 0) {
#pragma unroll
      for (int mt = 0; mt < 4; mt++)
#pragma unroll
        for (int r = 0; r < 4; r++) {
          int row = mt * 16 + quad * 4 + r;
          imPatch[dst][row] = (wv == 0) ? acc4[mt][r] : acc[2][mt][r];
        }
    }
  }
  __syncthreads();

#pragma unroll
  for (int mt = 0; mt < 4; mt++)
#pragma unroll
    for (int r = 0; r < 4; r++) {
      int row = mt * 16 + quad * 4 + r;
      int m = m0 + row;
      int b = m >> 2, t = m & 3;
      f16* orow = magP + (size_t)b * 832 + (t + 1) * 136;
      // col c0 = 32w + l15  (re tile 2w = slot0; im tiles slot2/slot3)
      {
        float re = acc[0][mt][r];
        float imA = __shfl(acc[2][mt][r], (quad << 4) | ((l15 + 1) & 15), 64);
        float imB = __shfl(acc[3][mt][r], quad << 4, 64);
        float im = (l15 == 15) ? imB : imA;
        orow[32 * wv + l15] = (f16)sqrtf(re * re + im * im);
      }
      // col c1 = 32w + 16 + l15 (re tile 2w+1 = slot1; im slot3 / patch)
      {
        float re = acc[1][mt][r];
        float imA = __shfl(acc[3][mt][r], (quad << 4) | ((l15 + 1) & 15), 64);
        float im = (l15 == 15) ? imPatch[wv][row] : imA;
        orow[32 * wv + 16 + l15] = (f16)sqrtf(re * re + im * im);
      }
      // col 128: wave0 only (re = tile8 col0 = slot2 @l15==0; im = tile16 col1)
      if (wv == 0) {
        float re = acc[2][mt][r];
        float im = __shfl(acc4[mt][r], (quad << 4) | 1, 64);
        if (l15 == 0) orow[128] = (f16)sqrtf(re * re + im * im);
      }
    }
}

// ---------------------------------------------------------------------------
// tail: conv1 -> conv2 -> conv3 -> conv4 -> gates -> LSTM -> decision.
// 32 batches per block (256 thr), all intermediates in LDS (region-aliased).
// LDS strides padded (+8 f16) so column-ish frag reads land on spread banks.
// ---------------------------------------------------------------------------
__global__ __launch_bounds__(256) void tail_kernel(
    const f16* __restrict__ magP, const f16* __restrict__ W1i,
    const float* __restrict__ b1, const f16* __restrict__ W2,
    const float* __restrict__ b2, const f16* __restrict__ W3,
    const float* __restrict__ b3, const f16* __restrict__ W4,
    const float* __restrict__ b4, const f16* __restrict__ Wg,
    const float* __restrict__ b_ih, const float* __restrict__ b_hh,
    const float* __restrict__ h0, const float* __restrict__ c0,
    const float* __restrict__ dec_w, const float* __restrict__ dec_b,
    float* __restrict__ out) {
  // regions: e1s [32][5][128] stride 648  @ elem 0      (41472 B)
  //          e2s [32][3][64]  stride 200  @ elem 20736  (12800 B)
  // aliased onto e1s after conv2:
  //          e3s [32][64+8]   stride 72   @ elem 0      (4608 B)
  //          e4h [32][256+8]  stride 264  @ elem 2304   (16896 B)
  //          part float[4][32]            @ byte 21504  (512 B)
  __shared__ __align__(16) char smem[54272];
  f16* SF = (f16*)smem;
  float* part = (float*)(smem + 21504);
#define E1(bl, s, c) ((bl) * 648 + (s) * 128 + (c))
#define E2(bl, s, c) (20736 + (bl) * 200 + (s) * 64 + (c))
#define E3(bl, c) ((bl) * 72 + (c))
#define E4(bl, k) (2304 + (bl) * 264 + (k))

  int tid = threadIdx.x;
  int lane = tid & 63, wv = tid >> 6;
  int l15 = lane & 15, quad = lane >> 4;
  int b0 = blockIdx.x * 32;
  f32x4 zero4 = {0.f, 0.f, 0.f, 0.f};

  // zero pads: e1 slot0, e2 slot0
  {
    f16x8 z8 = {};
    for (int idx = tid; idx < 512; idx += 256) {
      int bl = idx >> 4, g = idx & 15;
      *(f16x8*)&SF[E1(bl, 0, g * 8)] = z8;
    }
    for (int idx = tid; idx < 256; idx += 256) {
      int bl = idx >> 3, g = idx & 7;
      *(f16x8*)&SF[E2(bl, 0, g * 8)] = z8;
    }
  }

  // ---- conv1: M=128 rows (b,p), N=128, K=416. waves split N (2 tiles each),
  //      each wave covers all 8 m-tiles.
  {
    f32x4 acc1[8][2];
#pragma unroll
    for (int mt = 0; mt < 8; mt++)
#pragma unroll
      for (int nt = 0; nt < 2; nt++) acc1[mt][nt] = zero4;
    const f16* aptr[8];
#pragma unroll
    for (int mt = 0; mt < 8; mt++) {
      int row = mt * 16 + l15;
      int b = b0 + (row >> 2), p = row & 3;
      aptr[mt] = magP + (size_t)b * 832 + p * 136 + quad * 8;
    }
    const f16* bbase = W1i + ((2 * wv) * 16 + l15) * 32 + quad * 8;
    for (int kb = 0; kb < 13; kb++) {
      f16x8 a[8];
#pragma unroll
      for (int mt = 0; mt < 8; mt++) a[mt] = *(const f16x8*)(aptr[mt] + kb * 32);
      f16x8 bf0 = *(const f16x8*)(bbase + kb * 4096);
      f16x8 bf1 = *(const f16x8*)(bbase + kb * 4096 + 512);
#pragma unroll
      for (int mt = 0; mt < 8; mt++) {
        acc1[mt][0] = MFMA16(a[mt], bf0, acc1[mt][0]);
        acc1[mt][1] = MFMA16(a[mt], bf1, acc1[mt][1]);
      }
    }
    float bias[2];
#pragma unroll
    for (int nt = 0; nt < 2; nt++) bias[nt] = b1[(2 * wv + nt) * 16 + l15];
#pragma unroll
    for (int mt = 0; mt < 8; mt++)
#pragma unroll
      for (int r = 0; r < 4; r++) {
        int row = mt * 16 + quad * 4 + r;
        int bl = row >> 2, p = row & 3;
#pragma unroll
        for (int nt = 0; nt < 2; nt++) {
          int c = (2 * wv + nt) * 16 + l15;
          SF[E1(bl, p + 1, c)] = (f16)fmaxf(acc1[mt][nt][r] + bias[nt], 0.f);
        }
      }
  }
  __syncthreads();

  // ---- conv2: rows2 = bl*2+p2 (64), N=64, K=384. wave (wr=w&1, wc=w>>1).
  {
    int wr = wv & 1, wc = wv >> 1;
    f32x4 acc2[2][2];
#pragma unroll
    for (int mt = 0; mt < 2; mt++)
#pragma unroll
      for (int nt = 0; nt < 2; nt++) acc2[mt][nt] = zero4;
    int abase[2];
#pragma unroll
    for (int mt = 0; mt < 2; mt++) {
      int row2 = wr * 32 + mt * 16 + l15;
      int bl = row2 >> 1, p2 = row2 & 1;
      abase[mt] = E1(bl, 2 * p2, quad * 8);
    }
    const f16* bbase = W2 + (size_t)(wc * 32 + l15) * 384 + quad * 8;
    for (int kb = 0; kb < 12; kb++) {
      f16x8 a0 = *(const f16x8*)&SF[abase[0] + kb * 32];
      f16x8 a1 = *(const f16x8*)&SF[abase[1] + kb * 32];
      f16x8 bf0 = *(const f16x8*)(bbase + kb * 32);
      f16x8 bf1 = *(const f16x8*)(bbase + 16 * 384 + kb * 32);
      acc2[0][0] = MFMA16(a0, bf0, acc2[0][0]);
      acc2[1][0] = MFMA16(a1, bf0, acc2[1][0]);
      acc2[0][1] = MFMA16(a0, bf1, acc2[0][1]);
      acc2[1][1] = MFMA16(a1, bf1, acc2[1][1]);
    }
    float bias[2];
#pragma unroll
    for (int nt = 0; nt < 2; nt++) bias[nt] = b2[wc * 32 + nt * 16 + l15];
#pragma unroll
    for (int mt = 0; mt < 2; mt++)
#pragma unroll
      for (int r = 0; r < 4; r++) {
        int row2 = wr * 32 + mt * 16 + quad * 4 + r;
        int bl = row2 >> 1, p2 = row2 & 1;
#pragma unroll
        for (int nt = 0; nt < 2; nt++) {
          int c = wc * 32 + nt * 16 + l15;
          SF[E2(bl, p2 + 1, c)] = (f16)fmaxf(acc2[mt][nt][r] + bias[nt], 0.f);
        }
      }
  }
  __syncthreads();

  // ---- h0 -> e4h[:,128:256)  (e1 region now dead) + conv3
  {
    for (int idx = tid; idx < 1024; idx += 256) {
      int bl = idx >> 5, jg = idx & 31;
      const float4 v = *(const float4*)(h0 + (size_t)(b0 + bl) * 128 + jg * 4);
      f16x4 o = {(f16)v.x, (f16)v.y, (f16)v.z, (f16)v.w};
      *(f16x4*)&SF[E4(bl, 128 + jg * 4)] = o;
    }
    // conv3: M=32 (bl), N=64 (wave w: cols w*16), K=192
    f32x4 acc3[2];
#pragma unroll
    for (int mt = 0; mt < 2; mt++) acc3[mt] = zero4;
    const f16* bbase = W3 + (size_t)(wv * 16 + l15) * 192 + quad * 8;
    for (int kb = 0; kb < 6; kb++) {
      f16x8 a0 = *(const f16x8*)&SF[E2(l15, 0, 0) + kb * 32 + quad * 8];
      f16x8 a1 = *(const f16x8*)&SF[E2(16 + l15, 0, 0) + kb * 32 + quad * 8];
      f16x8 bf = *(const f16x8*)(bbase + kb * 32);
      acc3[0] = MFMA16(a0, bf, acc3[0]);
      acc3[1] = MFMA16(a1, bf, acc3[1]);
    }
    float bias = b3[wv * 16 + l15];
#pragma unroll
    for (int mt = 0; mt < 2; mt++)
#pragma unroll
      for (int r = 0; r < 4; r++) {
        int bl = mt * 16 + quad * 4 + r;
        SF[E3(bl, wv * 16 + l15)] = (f16)fmaxf(acc3[mt][r] + bias, 0.f);
      }
  }
  __syncthreads();

  // ---- conv4: M=32, N=128 (wave w: cols w*32), K=64
  {
    f32x4 acc4[2][2];
#pragma unroll
    for (int mt = 0; mt < 2; mt++)
#pragma unroll
      for (int nt = 0; nt < 2; nt++) acc4[mt][nt] = zero4;
    const f16* bbase = W4 + (size_t)(wv * 32 + l15) * 64 + quad * 8;
    for (int kb = 0; kb < 2; kb++) {
      f16x8 a0 = *(const f16x8*)&SF[E3(l15, kb * 32 + quad * 8)];
      f16x8 a1 = *(const f16x8*)&SF[E3(16 + l15, kb * 32 + quad * 8)];
      f16x8 bf0 = *(const f16x8*)(bbase + kb * 32);
      f16x8 bf1 = *(const f16x8*)(bbase + 16 * 64 + kb * 32);
      acc4[0][0] = MFMA16(a0, bf0, acc4[0][0]);
      acc4[1][0] = MFMA16(a1, bf0, acc4[1][0]);
      acc4[0][1] = MFMA16(a0, bf1, acc4[0][1]);
      acc4[1][1] = MFMA16(a1, bf1, acc4[1][1]);
    }
    float bias[2];
#pragma unroll
    for (int nt = 0; nt < 2; nt++) bias[nt] = b4[wv * 32 + nt * 16 + l15];
#pragma unroll
    for (int mt = 0; mt < 2; mt++)
#pragma unroll
      for (int r = 0; r < 4; r++) {
        int bl = mt * 16 + quad * 4 + r;
#pragma unroll
        for (int nt = 0; nt < 2; nt++) {
          int c = wv * 32 + nt * 16 + l15;
          SF[E4(bl, c)] = (f16)fmaxf(acc4[mt][nt][r] + bias[nt], 0.f);
        }
      }
  }
  __syncthreads();

  // ---- gates: M=32, N=512, K=256. wave w: tiles n0 = q*128 + w*32 + u*16.
  {
    f32x4 accg[8][2];  // [q*2+u][mt]
#pragma unroll
    for (int j = 0; j < 8; j++)
#pragma unroll
      for (int mt = 0; mt < 2; mt++) accg[j][mt] = zero4;
    const f16* bptrs[8];
#pragma unroll
    for (int q = 0; q < 4; q++)
#pragma unroll
      for (int u = 0; u < 2; u++)
        bptrs[q * 2 + u] =
            Wg + (size_t)(q * 128 + wv * 32 + u * 16 + l15) * 256 + quad * 8;
    for (int kb = 0; kb < 8; kb++) {
      f16x8 a0 = *(const f16x8*)&SF[E4(l15, kb * 32 + quad * 8)];
      f16x8 a1 = *(const f16x8*)&SF[E4(16 + l15, kb * 32 + quad * 8)];
#pragma unroll
      for (int j = 0; j < 8; j++) {
        f16x8 bf = *(const f16x8*)(bptrs[j] + kb * 32);
        accg[j][0] = MFMA16(a0, bf, accg[j][0]);
        accg[j][1] = MFMA16(a1, bf, accg[j][1]);
      }
    }
    float bias[8], dw[2];
#pragma unroll
    for (int q = 0; q < 4; q++)
#pragma unroll
      for (int u = 0; u < 2; u++) {
        int n = q * 128 + wv * 32 + u * 16 + l15;
        bias[q * 2 + u] = b_ih[n] + b_hh[n];
      }
#pragma unroll
    for (int u = 0; u < 2; u++) dw[u] = dec_w[wv * 32 + u * 16 + l15];

    float* out_h1 = out + BATCH;
    float* out_c1 = out + BATCH + (size_t)BATCH * 128;
#pragma unroll
    for (int mt = 0; mt < 2; mt++)
#pragma unroll
      for (int r = 0; r < 4; r++) {
        int bl = mt * 16 + quad * 4 + r;
        int b = b0 + bl;
        float p = 0.f;
#pragma unroll
        for (int u = 0; u < 2; u++) {
          int c = wv * 32 + u * 16 + l15;
          float iv = accg[0 + u][mt][r] + bias[0 + u];
          float fv = accg[2 + u][mt][r] + bias[2 + u];
          float gv = accg[4 + u][mt][r] + bias[4 + u];
          float ov = accg[6 + u][mt][r] + bias[6 + u];
          float c0v = c0[(size_t)b * 128 + c];
          float c1 = sigmoid_(fv) * c0v + sigmoid_(iv) * tanhf(gv);
          float h1 = sigmoid_(ov) * tanhf(c1);
          out_h1[(size_t)b * 128 + c] = h1;
          out_c1[(size_t)b * 128 + c] = c1;
          p += fmaxf(h1, 0.f) * dw[u];
        }
        p += __shfl_xor(p, 1);
        p += __shfl_xor(p, 2);
        p += __shfl_xor(p, 4);
        p += __shfl_xor(p, 8);
        if (l15 == 0) part[wv * 32 + bl] = p;
      }
  }
  __syncthreads();
  if (tid < 32) {
    float s = part[tid] + part[32 + tid] + part[64 + tid] + part[96 + tid] +
              dec_b[0];
    out[b0 + tid] = 1.f / (1.f + __expf(-s));
  }
#undef E1
#undef E2
#undef E3
#undef E4
}

// ---------------------------------------------------------------------------
extern "C" void kernel_launch(void* const* d_in, const int* in_sizes, int n_in,
                              void* d_out, int out_size, void* d_ws,
                              size_t ws_size, hipStream_t stream) {
  const float* x = (const float*)d_in[0];
  const float* h0 = (const float*)d_in[1];
  const float* c0 = (const float*)d_in[2];
  const float* basis = (const float*)d_in[3];
  const float* w1 = (const float*)d_in[4];
  const float* b1 = (const float*)d_in[5];
  const float* w2 = (const float*)d_in[6];
  const float* b2 = (const float*)d_in[7];
  const float* w3 = (const float*)d_in[8];
  const float* b3 = (const float*)d_in[9];
  const float* w4 = (const float*)d_in[10];
  const float* b4 = (const float*)d_in[11];
  const float* w_ih = (const float*)d_in[12];
  const float* w_hh = (const float*)d_in[13];
  const float* b_ih = (const float*)d_in[14];
  const float* b_hh = (const float*)d_in[15];
  const float* dec_w = (const float*)d_in[16];
  const float* dec_b = (const float*)d_in[17];

  char* ws = (char*)d_ws;
  f16* xp = (f16*)(ws + OFF_XP);
  f16* magP = (f16*)(ws + OFF_MAGP);
  f16* Bf3 = (f16*)(ws + OFF_BF);
  f16* W1i = (f16*)(ws + OFF_W1);
  f16* W2 = (f16*)(ws + OFF_W2);
  f16* W3 = (f16*)(ws + OFF_W3);
  f16* W4 = (f16*)(ws + OFF_W4);
  f16* Wg = (f16*)(ws + OFF_WG);

  prep_kernel<<<1088, 256, 0, stream>>>(x, basis, w1, w2, w3, w4, w_ih, w_hh,
                                        xp, magP, Bf3, W1i, W2, W3, W4, Wg);
  stft_kernel<<<2048, 256, 0, stream>>>(xp, Bf3, magP);
  tail_kernel<<<1024, 256, 0, stream>>>(magP, W1i, b1, W2, b2, W3, b3, W4, b4,
                                        Wg, b_ih, b_hh, h0, c0, dec_w, dec_b,
                                        (float*)d_out);
}

// Round 7
// 327.307 us; speedup vs baseline: 1.4924x; 1.0971x over previous
//
#include <hip/hip_runtime.h>

typedef _Float16 f16;
typedef _Float16 f16x8 __attribute__((ext_vector_type(8)));
typedef _Float16 f16x4 __attribute__((ext_vector_type(4)));
typedef float f32x4 __attribute__((ext_vector_type(4)));

#define MFMA16(a, b, c) __builtin_amdgcn_mfma_f32_16x16x32_f16((a), (b), (c), 0, 0, 0)

#define BATCH 32768

// workspace layout (bytes)
#define OFF_GATESA  ((size_t)0)                    // gatesA: B*256 f16 = 16,777,216
#define OFF_BF      (OFF_GATESA + 16777216)        // Bf3 [8][17][64][8] f16 = 139,264
#define OFF_W1      (OFF_BF + 139264)              // W1i [13][128][32] f16 = 106,496
#define OFF_W2      (OFF_W1 + 106496)              // [64][384]
#define OFF_W3      (OFF_W2 + 49152)               // [64][192]
#define OFF_W4      (OFF_W3 + 24576)               // [128][64]
#define OFF_WG      (OFF_W4 + 16384)               // [512][256]

__device__ __forceinline__ float sigmoid_(float x) { return 1.f / (1.f + __expf(-x)); }

// ---------------------------------------------------------------------------
// prep: h0 -> gatesA[:,128:256) (f16), and weight repacks.
// ---------------------------------------------------------------------------
__global__ __launch_bounds__(256) void prep_kernel(
    const float* __restrict__ h0, const float* __restrict__ basis,
    const float* __restrict__ w1, const float* __restrict__ w2,
    const float* __restrict__ w3, const float* __restrict__ w4,
    const float* __restrict__ w_ih, const float* __restrict__ w_hh,
    f16* __restrict__ gatesA, f16* __restrict__ Bf3, f16* __restrict__ W1i,
    f16* __restrict__ W2, f16* __restrict__ W3, f16* __restrict__ W4,
    f16* __restrict__ Wg) {
  int blk = blockIdx.x;
  int tid = threadIdx.x;
  if (blk < 1024) {
    int b0 = blk * 32;
    for (int idx = tid; idx < 32 * 32; idx += 256) {
      int bl = idx >> 5, g = idx & 31;
      const float4 v = *(const float4*)(h0 + (size_t)(b0 + bl) * 128 + g * 4);
      f16x4 o = {(f16)v.x, (f16)v.y, (f16)v.z, (f16)v.w};
      *(f16x4*)(gatesA + (size_t)(b0 + bl) * 256 + 128 + g * 4) = o;
    }
  } else {
    int t = (blk - 1024) * 256 + tid;  // 0..16383
    // basis -> Bf3 frag-major [kb][tile][lane][8]
    for (int idx = t; idx < 8 * 17 * 512; idx += 16384) {
      int jj = idx & 7;
      int lane = (idx >> 3) & 63;
      int rest = idx >> 9;
      int tt = rest % 17, kb = rest / 17;
      int n = tt * 16 + (lane & 15);
      int k = kb * 32 + (lane >> 4) * 8 + jj;
      Bf3[idx] = (f16)((n < 258) ? basis[n * 256 + k] : 0.f);
    }
    // w1 (128,129,3) -> W1i[kb][n][kk], logical k = tap*136 + i, K=416
    for (int idx = t; idx < 13 * 128 * 32; idx += 16384) {
      int kb = idx / 4096, rest = idx - kb * 4096;
      int n = rest >> 5, kk = rest & 31;
      int k = kb * 32 + kk;
      int tap = k / 136, i = k - tap * 136;
      float v = (tap < 3 && i < 129) ? w1[(n * 129 + i) * 3 + tap] : 0.f;
      W1i[idx] = (f16)v;
    }
    // w2 (64,128,3) -> W2[n][k], k = tap*128 + i, K=384
    for (int idx = t; idx < 64 * 384; idx += 16384) {
      int n = idx / 384, k = idx - n * 384;
      int tap = k >> 7, i = k & 127;
      W2[idx] = (f16)w2[(n * 128 + i) * 3 + tap];
    }
    // w3 (64,64,3) -> W3[n][k], k = tap*64 + i, K=192
    for (int idx = t; idx < 64 * 192; idx += 16384) {
      int n = idx / 192, k = idx - n * 192;
      int tap = k >> 6, i = k & 63;
      W3[idx] = (f16)w3[(n * 64 + i) * 3 + tap];
    }
    // w4 (128,64,3), only tap=1 contributes -> W4[n][i], K=64
    for (int idx = t; idx < 128 * 64; idx += 16384) {
      int n = idx >> 6, i = idx & 63;
      W4[idx] = (f16)w4[(n * 64 + i) * 3 + 1];
    }
    // Wg[512][256] = [w_ih | w_hh]
    for (int idx = t; idx < 512 * 256; idx += 16384) {
      int n = idx >> 8, k = idx & 255;
      Wg[idx] = (f16)((k < 128) ? w_ih[n * 128 + k] : w_hh[n * 128 + (k - 128)]);
    }
  }
}

// ---------------------------------------------------------------------------
// fused: x -> xpL(LDS) -> STFT -> mag(LDS) -> conv1..conv4 -> gatesA[:,0:128).
// 16 batches per 256-thr block, grid 2048. m = frame*16 + batch everywhere.
// LDS layout (57,088 B total) — de-aliased (R5 failed with a dense alias web):
//   A region  @ 0      (22,784 B): xpL [16][712] -> e1 [16][648] -> e3 [16][72]
//             (strict lifetime chain, each handoff across a __syncthreads)
//   magL      @ 22,784 (26,880 B): [16][840], DEDICATED, fully zeroed phase 0
//   e2        @ 49,664 ( 6,400 B): [16][200], DEDICATED, slot0 zeroed phase 0
//   imPatch   @ 56,064 ( 1,024 B): f32[4][64], DEDICATED
// ---------------------------------------------------------------------------
__global__ __launch_bounds__(256, 2) void fused_kernel(
    const float* __restrict__ x, const f16* __restrict__ Bf3,
    const f16* __restrict__ W1i, const float* __restrict__ b1,
    const f16* __restrict__ W2, const float* __restrict__ b2,
    const f16* __restrict__ W3, const float* __restrict__ b3,
    const f16* __restrict__ W4, const float* __restrict__ b4,
    f16* __restrict__ gatesA) {
  __shared__ __align__(16) char smem[57088];
  f16* SF = (f16*)smem;
  float* imPatch = (float*)(smem + 56064);  // dedicated
#define XP(bl, j) ((bl)*712 + (j))
#define E1(bl, s, c) ((bl)*648 + (s)*128 + (c))
#define E3(bl, c) ((bl)*72 + (c))
#define MG(bl, j) (11392 + (bl)*840 + (j))
#define E2(bl, s, c) (24832 + (bl)*200 + (s)*64 + (c))

  int tid = threadIdx.x;
  int lane = tid & 63, wv = tid >> 6;
  int l15 = lane & 15, quad = lane >> 4;
  int b0 = blockIdx.x * 16;
  f32x4 zero4 = {0.f, 0.f, 0.f, 0.f};

  // ---- phase 0: build xpL; zero ALL of magL (incl. gaps: stale LDS there is
  //      multiplied by zero weights — must not be Inf/NaN); zero e2 slot0. ----
  for (int idx = tid; idx < 16 * 176; idx += 256) {
    int bl = idx / 176, g = idx - bl * 176;
    int b = b0 + bl;
    f16x4 o;
    if (g < 32) {
      float v0 = (g == 0) ? x[(size_t)b * 512] : 0.f;
      o = (f16x4){(f16)v0, (f16)0.f, (f16)0.f, (f16)0.f};
    } else if (g < 160) {
      const float4 v = *(const float4*)(x + (size_t)b * 512 + 4 * g - 128);
      o = (f16x4){(f16)v.x, (f16)v.y, (f16)v.z, (f16)v.w};
    } else {
      int j0 = 4 * g;  // [640,704)
      const float* xb = x + (size_t)b * 512;
      o = (f16x4){(f16)xb[1150 - j0], (f16)xb[1149 - j0], (f16)xb[1148 - j0],
                  (f16)xb[1147 - j0]};
    }
    *(f16x4*)&SF[XP(bl, 4 * g)] = o;
  }
  {
    f16x8 z8 = {};
    for (int idx = tid; idx < 16 * 105; idx += 256) {  // full magL (840=105*8)
      int bl = idx / 105, g = idx - bl * 105;
      *(f16x8*)&SF[MG(bl, g * 8)] = z8;
    }
    for (int idx = tid; idx < 16 * 8; idx += 256) {  // e2 slot0 (dedicated now)
      int bl = idx >> 3, g = idx & 7;
      *(f16x8*)&SF[E2(bl, 0, g * 8)] = z8;
    }
  }
  __syncthreads();

  // ---- STFT: M=64 (m = frame*16 + batch); wave w tiles {2w,2w+1,2w+8,2w+9},
  //      wave0 also tile16. B streams from L2, reg double-buffered. ----
  {
    int t0 = 2 * wv, t1 = t0 + 1, t2 = t0 + 8, t3 = t0 + 9;
    f32x4 acc[4][4];  // [slot][mt]
    f32x4 acc4[4];
#pragma unroll
    for (int s = 0; s < 4; s++)
#pragma unroll
      for (int mt = 0; mt < 4; mt++) acc[s][mt] = zero4;
#pragma unroll
    for (int mt = 0; mt < 4; mt++) acc4[mt] = zero4;

    const f16* Bl = Bf3 + lane * 8;
    f16x8 bc0 = *(const f16x8*)(Bl + t0 * 512);
    f16x8 bc1 = *(const f16x8*)(Bl + t1 * 512);
    f16x8 bc2 = *(const f16x8*)(Bl + t2 * 512);
    f16x8 bc3 = *(const f16x8*)(Bl + t3 * 512);
    f16x8 bc4 = {};
    if (wv == 0) bc4 = *(const f16x8*)(Bl + 16 * 512);

    for (int kb = 0; kb < 8; kb++) {
      f16x8 bn0, bn1, bn2, bn3, bn4;
      if (kb < 7) {
        const f16* Bn = Bl + (size_t)(kb + 1) * 17 * 512;
        bn0 = *(const f16x8*)(Bn + t0 * 512);
        bn1 = *(const f16x8*)(Bn + t1 * 512);
        bn2 = *(const f16x8*)(Bn + t2 * 512);
        bn3 = *(const f16x8*)(Bn + t3 * 512);
        if (wv == 0) bn4 = *(const f16x8*)(Bn + 16 * 512);
      }
      f16x8 a[4];
#pragma unroll
      for (int mt = 0; mt < 4; mt++)
        a[mt] = *(const f16x8*)&SF[XP(l15, mt * 128 + kb * 32 + quad * 8)];
#pragma unroll
      for (int mt = 0; mt < 4; mt++) {
        acc[0][mt] = MFMA16(a[mt], bc0, acc[0][mt]);
        acc[1][mt] = MFMA16(a[mt], bc1, acc[1][mt]);
        acc[2][mt] = MFMA16(a[mt], bc2, acc[2][mt]);
        acc[3][mt] = MFMA16(a[mt], bc3, acc[3][mt]);
      }
      if (wv == 0) {
#pragma unroll
        for (int mt = 0; mt < 4; mt++) acc4[mt] = MFMA16(a[mt], bc4, acc4[mt]);
      }
      if (kb < 7) {
        bc0 = bn0; bc1 = bn1; bc2 = bn2; bc3 = bn3;
        if (wv == 0) bc4 = bn4;
      }
    }

    // imPatch is dedicated: no hazard with xpL. Publish boundary columns.
    {
      int dst = (wv == 0) ? 3 : (wv - 1);
      if (l15 == 0) {
#pragma unroll
        for (int mt = 0; mt < 4; mt++)
#pragma unroll
          for (int r = 0; r < 4; r++) {
            int row = mt * 16 + quad * 4 + r;
            imPatch[dst * 64 + row] = (wv == 0) ? acc4[mt][r] : acc[2][mt][r];
          }
      }
    }
    __syncthreads();

#pragma unroll
    for (int mt = 0; mt < 4; mt++)
#pragma unroll
      for (int r = 0; r < 4; r++) {
        int bl = quad * 4 + r;  // batch
        int orow = MG(bl, (mt + 1) * 136);
        {
          float re = acc[0][mt][r];
          float imA = __shfl(acc[2][mt][r], (quad << 4) | ((l15 + 1) & 15), 64);
          float imB = __shfl(acc[3][mt][r], quad << 4, 64);
          float im = (l15 == 15) ? imB : imA;
          SF[orow + 32 * wv + l15] = (f16)sqrtf(re * re + im * im);
        }
        {
          float re = acc[1][mt][r];
          float imA = __shfl(acc[3][mt][r], (quad << 4) | ((l15 + 1) & 15), 64);
          int row = mt * 16 + quad * 4 + r;
          float im = (l15 == 15) ? imPatch[wv * 64 + row] : imA;
          SF[orow + 32 * wv + 16 + l15] = (f16)sqrtf(re * re + im * im);
        }
        if (wv == 0) {
          float re = acc[2][mt][r];
          float im = __shfl(acc4[mt][r], (quad << 4) | 1, 64);
          if (l15 == 0) SF[orow + 128] = (f16)sqrtf(re * re + im * im);
        }
      }
  }
  __syncthreads();

  // ---- conv1: M=64 (m = p*16 + bl), N=128 (wave w: tiles 2w,2w+1), K=416.
  //      e1 takes over the A region (xpL dead past the barrier above). ----
  {
    f16x8 z8 = {};
    for (int idx = tid; idx < 16 * 16; idx += 256) {
      int bl = idx >> 4, g = idx & 15;
      *(f16x8*)&SF[E1(bl, 0, g * 8)] = z8;  // zero e1 slot0
    }
    f32x4 acc1[4][2];
#pragma unroll
    for (int p = 0; p < 4; p++)
#pragma unroll
      for (int nt = 0; nt < 2; nt++) acc1[p][nt] = zero4;
    const f16* bbase = W1i + ((2 * wv) * 16 + l15) * 32 + quad * 8;
    f16x8 bc0 = *(const f16x8*)(bbase);
    f16x8 bc1 = *(const f16x8*)(bbase + 512);
    for (int kb = 0; kb < 13; kb++) {
      f16x8 bn0, bn1;
      if (kb < 12) {
        bn0 = *(const f16x8*)(bbase + (kb + 1) * 4096);
        bn1 = *(const f16x8*)(bbase + (kb + 1) * 4096 + 512);
      }
      f16x8 a[4];
#pragma unroll
      for (int p = 0; p < 4; p++)
        a[p] = *(const f16x8*)&SF[MG(l15, p * 136 + kb * 32 + quad * 8)];
#pragma unroll
      for (int p = 0; p < 4; p++) {
        acc1[p][0] = MFMA16(a[p], bc0, acc1[p][0]);
        acc1[p][1] = MFMA16(a[p], bc1, acc1[p][1]);
      }
      if (kb < 12) { bc0 = bn0; bc1 = bn1; }
    }
    float bias[2];
#pragma unroll
    for (int nt = 0; nt < 2; nt++) bias[nt] = b1[(2 * wv + nt) * 16 + l15];
#pragma unroll
    for (int p = 0; p < 4; p++)
#pragma unroll
      for (int r = 0; r < 4; r++) {
        int bl = quad * 4 + r;
#pragma unroll
        for (int nt = 0; nt < 2; nt++) {
          int c = (2 * wv + nt) * 16 + l15;
          SF[E1(bl, p + 1, c)] = (f16)fmaxf(acc1[p][nt][r] + bias[nt], 0.f);
        }
      }
  }
  __syncthreads();

  // ---- conv2: wave wr=wv&1 -> output position, wc=wv>>1 -> col half.
  //      K=384 from e1; writes e2 slots 1..2 (dedicated region). ----
  {
    int wr = wv & 1, wc = wv >> 1;
    f32x4 acc2[2] = {zero4, zero4};
    const f16* bbase = W2 + (size_t)(wc * 32 + l15) * 384 + quad * 8;
    f16x8 bc0 = *(const f16x8*)(bbase);
    f16x8 bc1 = *(const f16x8*)(bbase + 16 * 384);
    for (int kb = 0; kb < 12; kb++) {
      f16x8 bn0, bn1;
      if (kb < 11) {
        bn0 = *(const f16x8*)(bbase + (kb + 1) * 32);
        bn1 = *(const f16x8*)(bbase + 16 * 384 + (kb + 1) * 32);
      }
      f16x8 a = *(const f16x8*)&SF[E1(l15, wr * 2, kb * 32 + quad * 8)];
      acc2[0] = MFMA16(a, bc0, acc2[0]);
      acc2[1] = MFMA16(a, bc1, acc2[1]);
      if (kb < 11) { bc0 = bn0; bc1 = bn1; }
    }
    float bias[2] = {b2[wc * 32 + l15], b2[wc * 32 + 16 + l15]};
#pragma unroll
    for (int r = 0; r < 4; r++) {
      int bl = quad * 4 + r;
      SF[E2(bl, wr + 1, wc * 32 + l15)] = (f16)fmaxf(acc2[0][r] + bias[0], 0.f);
      SF[E2(bl, wr + 1, wc * 32 + 16 + l15)] =
          (f16)fmaxf(acc2[1][r] + bias[1], 0.f);
    }
  }
  __syncthreads();

  // ---- conv3: M=16, N=64 (wave w: cols w*16), K=192 from e2.
  //      e3 takes over the A region head (e1 dead past the barrier). ----
  {
    f32x4 acc3 = zero4;
    const f16* bbase = W3 + (size_t)(wv * 16 + l15) * 192 + quad * 8;
    for (int kb = 0; kb < 6; kb++) {
      f16x8 a = *(const f16x8*)&SF[E2(l15, 0, kb * 32 + quad * 8)];
      f16x8 bf = *(const f16x8*)(bbase + kb * 32);
      acc3 = MFMA16(a, bf, acc3);
    }
    float bias = b3[wv * 16 + l15];
#pragma unroll
    for (int r = 0; r < 4; r++) {
      int bl = quad * 4 + r;
      SF[E3(bl, wv * 16 + l15)] = (f16)fmaxf(acc3[r] + bias, 0.f);
    }
  }
  __syncthreads();

  // ---- conv4: M=16, N=128 (wave w: cols w*32), K=64 -> gatesA[:,0:128) ----
  {
    f32x4 acc4a[2] = {zero4, zero4};
    const f16* bbase = W4 + (size_t)(wv * 32 + l15) * 64 + quad * 8;
    for (int kb = 0; kb < 2; kb++) {
      f16x8 a = *(const f16x8*)&SF[E3(l15, kb * 32 + quad * 8)];
      f16x8 bf0 = *(const f16x8*)(bbase + kb * 32);
      f16x8 bf1 = *(const f16x8*)(bbase + 16 * 64 + kb * 32);
      acc4a[0] = MFMA16(a, bf0, acc4a[0]);
      acc4a[1] = MFMA16(a, bf1, acc4a[1]);
    }
    float bias[2] = {b4[wv * 32 + l15], b4[wv * 32 + 16 + l15]};
#pragma unroll
    for (int r = 0; r < 4; r++) {
      int bl = quad * 4 + r;
      gatesA[(size_t)(b0 + bl) * 256 + wv * 32 + l15] =
          (f16)fmaxf(acc4a[0][r] + bias[0], 0.f);
      gatesA[(size_t)(b0 + bl) * 256 + wv * 32 + 16 + l15] =
          (f16)fmaxf(acc4a[1][r] + bias[1], 0.f);
    }
  }
#undef XP
#undef MG
#undef E1
#undef E2
#undef E3
}

// ---------------------------------------------------------------------------
// gates GEMM + LSTM cell + decision head (M=64/block, verified in R2/R3).
// ---------------------------------------------------------------------------
__global__ __launch_bounds__(256) void gates_kernel(
    const f16* __restrict__ gatesA, const f16* __restrict__ Wg,
    const float* __restrict__ b_ih, const float* __restrict__ b_hh,
    const float* __restrict__ c0, const float* __restrict__ dec_w,
    const float* __restrict__ dec_b, float* __restrict__ out) {
  __shared__ float part[4][64];
  int tid = threadIdx.x;
  int lane = tid & 63, wv = tid >> 6;
  int l15 = lane & 15, quad = lane >> 4;
  int b0 = blockIdx.x * 64;
  f32x4 zero4 = {0.f, 0.f, 0.f, 0.f};

  float* out_h1 = out + BATCH;
  float* out_c1 = out + BATCH + (size_t)BATCH * 128;

  f32x4 acc[4][8];  // [mt][q*2+u]
#pragma unroll
  for (int mt = 0; mt < 4; mt++)
#pragma unroll
    for (int j = 0; j < 8; j++) acc[mt][j] = zero4;

  const f16* aptr[4];
#pragma unroll
  for (int mt = 0; mt < 4; mt++)
    aptr[mt] = gatesA + (size_t)(b0 + mt * 16 + l15) * 256 + quad * 8;

  const f16* bptrs[8];
#pragma unroll
  for (int q = 0; q < 4; q++)
#pragma unroll
    for (int u = 0; u < 2; u++)
      bptrs[q * 2 + u] =
          Wg + (size_t)(q * 128 + wv * 32 + u * 16 + l15) * 256 + quad * 8;

  for (int k0 = 0; k0 < 256; k0 += 32) {
    f16x8 a[4];
#pragma unroll
    for (int mt = 0; mt < 4; mt++) a[mt] = *(const f16x8*)(aptr[mt] + k0);
#pragma unroll
    for (int j = 0; j < 8; j++) {
      f16x8 bf = *(const f16x8*)(bptrs[j] + k0);
#pragma unroll
      for (int mt = 0; mt < 4; mt++) acc[mt][j] = MFMA16(a[mt], bf, acc[mt][j]);
    }
  }

  float bias[8], dw[2];
#pragma unroll
  for (int q = 0; q < 4; q++)
#pragma unroll
    for (int u = 0; u < 2; u++) {
      int n = q * 128 + wv * 32 + u * 16 + l15;
      bias[q * 2 + u] = b_ih[n] + b_hh[n];
    }
#pragma unroll
  for (int u = 0; u < 2; u++) dw[u] = dec_w[wv * 32 + u * 16 + l15];

#pragma unroll
  for (int mt = 0; mt < 4; mt++)
#pragma unroll
    for (int r = 0; r < 4; r++) {
      int bl = mt * 16 + quad * 4 + r;
      int b = b0 + bl;
      float p = 0.f;
#pragma unroll
      for (int u = 0; u < 2; u++) {
        int c = wv * 32 + u * 16 + l15;
        float iv = acc[mt][0 + u][r] + bias[0 + u];
        float fv = acc[mt][2 + u][r] + bias[2 + u];
        float gv = acc[mt][4 + u][r] + bias[4 + u];
        float ov = acc[mt][6 + u][r] + bias[6 + u];
        float c0v = c0[(size_t)b * 128 + c];
        float c1 = sigmoid_(fv) * c0v + sigmoid_(iv) * tanhf(gv);
        float h1 = sigmoid_(ov) * tanhf(c1);
        out_h1[(size_t)b * 128 + c] = h1;
        out_c1[(size_t)b * 128 + c] = c1;
        p += fmaxf(h1, 0.f) * dw[u];
      }
      p += __shfl_xor(p, 1);
      p += __shfl_xor(p, 2);
      p += __shfl_xor(p, 4);
      p += __shfl_xor(p, 8);
      if (l15 == 0) part[wv][bl] = p;
    }
  __syncthreads();
  if (tid < 64) {
    float s = part[0][tid] + part[1][tid] + part[2][tid] + part[3][tid] +
              dec_b[0];
    out[b0 + tid] = 1.f / (1.f + __expf(-s));
  }
}

// ---------------------------------------------------------------------------
extern "C" void kernel_launch(void* const* d_in, const int* in_sizes, int n_in,
                              void* d_out, int out_size, void* d_ws,
                              size_t ws_size, hipStream_t stream) {
  const float* x = (const float*)d_in[0];
  const float* h0 = (const float*)d_in[1];
  const float* c0 = (const float*)d_in[2];
  const float* basis = (const float*)d_in[3];
  const float* w1 = (const float*)d_in[4];
  const float* b1 = (const float*)d_in[5];
  const float* w2 = (const float*)d_in[6];
  const float* b2 = (const float*)d_in[7];
  const float* w3 = (const float*)d_in[8];
  const float* b3 = (const float*)d_in[9];
  const float* w4 = (const float*)d_in[10];
  const float* b4 = (const float*)d_in[11];
  const float* w_ih = (const float*)d_in[12];
  const float* w_hh = (const float*)d_in[13];
  const float* b_ih = (const float*)d_in[14];
  const float* b_hh = (const float*)d_in[15];
  const float* dec_w = (const float*)d_in[16];
  const float* dec_b = (const float*)d_in[17];

  char* ws = (char*)d_ws;
  f16* gatesA = (f16*)(ws + OFF_GATESA);
  f16* Bf3 = (f16*)(ws + OFF_BF);
  f16* W1i = (f16*)(ws + OFF_W1);
  f16* W2 = (f16*)(ws + OFF_W2);
  f16* W3 = (f16*)(ws + OFF_W3);
  f16* W4 = (f16*)(ws + OFF_W4);
  f16* Wg = (f16*)(ws + OFF_WG);

  prep_kernel<<<1088, 256, 0, stream>>>(h0, basis, w1, w2, w3, w4, w_ih, w_hh,
                                        gatesA, Bf3, W1i, W2, W3, W4, Wg);
  fused_kernel<<<2048, 256, 0, stream>>>(x, Bf3, W1i, b1, W2, b2, W3, b3, W4,
                                         b4, gatesA);
  gates_kernel<<<512, 256, 0, stream>>>(gatesA, Wg, b_ih, b_hh, c0, dec_w,
                                        dec_b, (float*)d_out);
}